// Round 7
// baseline (659.152 us; speedup 1.0000x reference)
//
#include <hip/hip_runtime.h>
#include <hip/hip_bf16.h>

#define CDIV(a,b) (((a)+(b)-1)/(b))
#define NBUCK_MAX 512   // 128-node ebuf buckets; supports N up to 65536 (ebuf packing needs N<=65536)
#define FUSE_CAP 1536   // staged csr entries per 64-node bfuse item
#define CAPL     4096   // fuse1 csr window (fills the 16KB sBL4 region)
#define AGGF_CAP 2048   // aggf csr window

typedef __attribute__((ext_vector_type(8))) short short8;
typedef __attribute__((ext_vector_type(4))) float f32x4;
typedef __attribute__((ext_vector_type(2))) float f32x2;

static __device__ __forceinline__ unsigned short f2bf(float f){
  union { float f; unsigned u; } v; v.f = f;
  unsigned r = v.u + 0x7fffu + ((v.u >> 16) & 1u);   // RNE
  return (unsigned short)(r >> 16);
}
static __device__ __forceinline__ unsigned pack2(float lo, float hi){
  return (unsigned)f2bf(lo) | ((unsigned)f2bf(hi) << 16);
}
static __device__ __forceinline__ float bf2f(unsigned short s){
  union { unsigned u; float f; } v; v.u = ((unsigned)s) << 16; return v.f;
}
static __device__ __forceinline__ unsigned pk_fp8x4(float a, float b, float c, float d){
  int v = __builtin_amdgcn_cvt_pk_fp8_f32(a, b, 0, false);
  v = __builtin_amdgcn_cvt_pk_fp8_f32(c, d, v, true);
  return (unsigned)v;
}

#define ACCP16(v) { b0 += __builtin_amdgcn_cvt_pk_f32_fp8((int)v.x, false); \
                    b1 += __builtin_amdgcn_cvt_pk_f32_fp8((int)v.x, true);  \
                    b2 += __builtin_amdgcn_cvt_pk_f32_fp8((int)v.y, false); \
                    b3 += __builtin_amdgcn_cvt_pk_f32_fp8((int)v.y, true);  \
                    b4 += __builtin_amdgcn_cvt_pk_f32_fp8((int)v.z, false); \
                    b5 += __builtin_amdgcn_cvt_pk_f32_fp8((int)v.z, true);  \
                    b6 += __builtin_amdgcn_cvt_pk_f32_fp8((int)v.w, false); \
                    b7 += __builtin_amdgcn_cvt_pk_f32_fp8((int)v.w, true); }

// ---------------- weight pack ----------------
// perm: first-128 K positions hold channel pi(k) = (k&7)*16 + (k>>3)

struct WtpArgs {
  const float *W0, *W1, *bl, *g, *b, *rm, *rv;
  unsigned short* Bpk; float *sc; float *sh;
  int kblk, dout, do_bn, nblk, perm;
};

static __device__ __forceinline__ void wtp_one(const WtpArgs& a, int idx){
  int NB16 = a.kblk*32*a.dout;
  if (idx < NB16){
    int j = idx & 7, lane = (idx >> 3) & 63, rest = idx >> 9;
    int NT = a.dout >> 4;
    int nt = rest % NT, kk = rest / NT;
    int nn = nt*16 + (lane & 15);
    int k  = kk*32 + ((lane >> 4) * 8) + j;
    float v;
    if (k < 128){
      int kc = a.perm ? (((k & 7) << 4) | (k >> 3)) : k;
      v = a.W0[nn*128 + kc];
    } else {
      v = a.W1[nn*128 + (k - 128)];
    }
    a.Bpk[idx] = f2bf(v);
  } else if (a.do_bn && idx < NB16 + a.dout){
    int jj = idx - NB16;
    float s = a.g[jj] * rsqrtf(a.rv[jj] + 1e-5f);
    a.sc[jj] = s;
    a.sh[jj] = (a.bl[jj] - a.rm[jj]) * s + a.b[jj];
  }
}

// ---------------- mega-kernel args ----------------

struct MegaArgs {
  const float* x; int n4;
  unsigned* xb; unsigned* xq;
  const int* esrc; const int* edst;
  int E, N, nbuck;
  int* bcnt; int* bcur;
  int* barCnt; int* barEpoch;
  int* off; int* csr; unsigned* ebuf;
  const unsigned short* Bpk0; const unsigned short* Bpk1;
  const unsigned short* BpkL; const unsigned short* BpkR;
  const float *sc0, *sh0, *sc1, *sh1, *sc2, *sh2;
  unsigned short* h_a; unsigned short* h_b;
  unsigned* haq; unsigned* ylb;
  float* outf;
  int castBlocks, histBlocks, p0Total, aBlocks, nb2, nblk;
  WtpArgs wa0, wa1, wa2, wa3;
};

// device-wide epoch barrier (agent scope; release flush + acquire inv)
static __device__ __forceinline__ void gbar(int* cnt, int* epoch, int nblk, int eps){
  __syncthreads();
  if (threadIdx.x == 0){
    __threadfence();
    int prev = __hip_atomic_fetch_add(cnt, 1, __ATOMIC_ACQ_REL, __HIP_MEMORY_SCOPE_AGENT);
    if (prev == nblk - 1){
      __hip_atomic_store(cnt, 0, __ATOMIC_RELAXED, __HIP_MEMORY_SCOPE_AGENT);
      __hip_atomic_fetch_add(epoch, 1, __ATOMIC_RELEASE, __HIP_MEMORY_SCOPE_AGENT);
    } else {
      while (__hip_atomic_load(epoch, __ATOMIC_ACQUIRE, __HIP_MEMORY_SCOPE_AGENT) < eps){
        __builtin_amdgcn_s_sleep(2);
      }
    }
  }
  __syncthreads();
  __threadfence();
}

// ---------------- P0: cast x -> bf16+fp8 | edge histogram | weight pack ----------------

static __device__ void p0_prep(int b, uint4* pool4, const MegaArgs& A){
  int* s = (int*)pool4;
  int t = threadIdx.x;
  __syncthreads();
  if (b < A.castBlocks){
    int i = b*256 + t;
    if (i < A.n4){
      float4 v = ((const float4*)A.x)[i];
      uint2 o; o.x = pack2(v.x, v.y); o.y = pack2(v.z, v.w);
      ((uint2*)A.xb)[i] = o;
      A.xq[i] = pk_fp8x4(v.x, v.y, v.z, v.w);
    }
    return;
  }
  b -= A.castBlocks;
  if (b < A.histBlocks){
    for (int i=t;i<A.nbuck;i+=256) s[i] = 0;
    __syncthreads();
    constexpr int EPT = 16;
    int e0 = b*256*EPT;
    #pragma unroll
    for (int i=0;i<EPT;i++){
      int e = e0 + i*256 + t;
      if (e < A.E) atomicAdd(&s[A.edst[e] >> 7], 1);
    }
    __syncthreads();
    for (int i=t;i<A.nbuck;i+=256){
      int c = s[i];
      if (c > 0) atomicAdd(&A.bcnt[i], c);
    }
    return;
  }
  b -= A.histBlocks;
  if (b < A.wa0.nblk){ wtp_one(A.wa0, b*256 + t); return; }
  b -= A.wa0.nblk;
  if (b < A.wa1.nblk){ wtp_one(A.wa1, b*256 + t); return; }
  b -= A.wa1.nblk;
  if (b < A.wa2.nblk){ wtp_one(A.wa2, b*256 + t); return; }
  b -= A.wa2.nblk;
  wtp_one(A.wa3, b*256 + t);
}

// ---------------- P1: bin edges into 128-node ebuf buckets ----------------

static __device__ void p1_bucketA(int blk, uint4* pool4, const MegaArgs& A){
  int* scnt  = (int*)pool4;
  int* sbase = scnt + NBUCK_MAX;
  int* sboff = sbase + NBUCK_MAX;
  int* ss    = sboff + NBUCK_MAX;
  int t = threadIdx.x;
  __syncthreads();
  {
    int a0 = (2*t   < A.nbuck) ? A.bcnt[2*t]   : 0;
    int a1 = (2*t+1 < A.nbuck) ? A.bcnt[2*t+1] : 0;
    ss[t] = a0 + a1; __syncthreads();
    for (int d=1; d<256; d<<=1){
      int u = (t>=d) ? ss[t-d] : 0;
      __syncthreads();
      ss[t] += u;
      __syncthreads();
    }
    int excl = ss[t] - (a0 + a1);
    if (2*t   < A.nbuck) sboff[2*t]   = excl;
    if (2*t+1 < A.nbuck) sboff[2*t+1] = excl + a0;
  }
  for (int i=t;i<A.nbuck;i+=256) scnt[i] = 0;
  __syncthreads();
  constexpr int EPT = 8;
  int e0 = blk*256*EPT;
  int bb[EPT]; unsigned pk[EPT];
  #pragma unroll
  for (int i=0;i<EPT;i++){
    int e = e0 + i*256 + t;
    if (e < A.E){
      int d = A.edst[e];
      bb[i] = d >> 7;
      pk[i] = ((unsigned)(d & 127) << 16) | (unsigned)A.esrc[e];
      atomicAdd(&scnt[bb[i]], 1);
    } else bb[i] = -1;
  }
  __syncthreads();
  for (int i=t;i<A.nbuck;i+=256){
    int c = scnt[i];
    sbase[i] = (c > 0) ? atomicAdd(&A.bcur[i], c) : 0;
    scnt[i] = 0;
  }
  __syncthreads();
  #pragma unroll
  for (int i=0;i<EPT;i++){
    if (bb[i] >= 0){
      int p = atomicAdd(&scnt[bb[i]], 1);
      A.ebuf[(size_t)sboff[bb[i]] + sbase[bb[i]] + p] = pk[i];
    }
  }
}

// ---------------- P2: csr build + fused layer-0 (64-node items; 2 items per 128-node ebuf window) ----------------

static __device__ void p2_bfuse(int wb, uint4* pool4, const MegaArgs& A){
  uint4* Ms4 = pool4;                       // 1088 u4 = 17408 B
  int* scsr  = (int*)(pool4 + 1088);        // FUSE_CAP ints
  int* sEx   = (int*)(pool4 + 1472);        // NBUCK_MAX ints
  int* ss    = (int*)(pool4 + 1600);        // 256 ints
  unsigned short* Ms = (unsigned short*)Ms4;
  int* sdeg = (int*)Ms4;                    // [128]
  int* sabs = sdeg + 128;                   // [129]
  int* cur  = sabs + 129;                   // [128]
  int b = wb >> 1, hi = wb & 1;
  int t = threadIdx.x;
  __syncthreads();
  {
    int a0 = (2*t   < A.nbuck) ? A.bcnt[2*t]   : 0;
    int a1 = (2*t+1 < A.nbuck) ? A.bcnt[2*t+1] : 0;
    ss[t] = a0 + a1; __syncthreads();
    for (int d=1; d<256; d<<=1){
      int u = (t>=d) ? ss[t-d] : 0;
      __syncthreads();
      ss[t] += u;
      __syncthreads();
    }
    int excl = ss[t] - (a0 + a1);
    if (2*t   < A.nbuck) sEx[2*t]   = excl;
    if (2*t+1 < A.nbuck) sEx[2*t+1] = excl + a0;
  }
  if (t < 128){ sdeg[t] = 0; cur[t] = 0; }
  __syncthreads();
  int e0 = sEx[b];
  int e1 = (b+1 < A.nbuck) ? sEx[b+1] : A.E;
  for (int e = e0 + t; e < e1; e += 256)
    atomicAdd(&sdeg[A.ebuf[e] >> 16], 1);
  __syncthreads();
  for (int d=1; d<128; d<<=1){
    int u = (t < 128 && t >= d) ? sdeg[t-d] : 0;
    __syncthreads();
    if (t < 128) sdeg[t] += u;
    __syncthreads();
  }
  if (t == 0) sabs[0] = 0;
  if (t < 128) sabs[t+1] = sdeg[t];
  __syncthreads();
  int base64 = sabs[hi*64];
  int myTot  = sabs[hi*64 + 64] - base64;
  int n0 = (b << 7) + hi*64;
  int cnt = (A.N > n0) ? min(64, A.N - n0) : 0;
  if (cnt > 0 && t <= cnt) A.off[n0 + t] = e0 + sabs[hi*64 + t];
  int lane = t & 63, w = t >> 6, sl = lane & 7;
  int gs0[2], gs1[2];
  #pragma unroll
  for (int it=0; it<2; it++){
    int rk = w*16 + it*8 + (lane >> 3);
    gs0[it] = sabs[hi*64 + rk] - base64;
    gs1[it] = sabs[hi*64 + rk + 1] - base64;
  }
  bool fits = myTot <= FUSE_CAP;
  for (int e = e0 + t; e < e1; e += 256){
    unsigned pr = A.ebuf[e];
    int ln = (int)(pr >> 16);
    if ((ln >> 6) == hi){
      int p = atomicAdd(&cur[ln], 1);
      int gpos = sabs[ln] + p;
      int sv = (int)(pr & 0xffffu);
      if (fits) scsr[gpos - base64] = sv;
      else      A.csr[e0 + gpos] = sv;
    }
  }
  __syncthreads();
  const int* gcsr = A.csr + e0 + base64;
  if (fits){
    for (int i = t; i < myTot; i += 256) A.csr[e0 + base64 + i] = scsr[i];
  } else {
    for (int i = t; i < FUSE_CAP; i += 256) scsr[i] = gcsr[i];
    __syncthreads();
  }

  const uint4* xq4 = (const uint4*)A.xq;
  #pragma unroll
  for (int it=0; it<2; it++){
    int rk = w*16 + it*8 + (lane >> 3);
    int s0 = gs0[it], s1 = gs1[it];
    f32x2 b0={0,0},b1={0,0},b2={0,0},b3={0,0},b4={0,0},b5={0,0},b6={0,0},b7={0,0};
    int e = s0;
    for (; e + 8 <= s1; e += 8){
      int i0,i1,i2,i3,i4,i5,i6,i7;
      if (e + 8 <= FUSE_CAP){
        i0 = scsr[e];   i1 = scsr[e+1]; i2 = scsr[e+2]; i3 = scsr[e+3];
        i4 = scsr[e+4]; i5 = scsr[e+5]; i6 = scsr[e+6]; i7 = scsr[e+7];
      } else {
        i0 = gcsr[e];   i1 = gcsr[e+1]; i2 = gcsr[e+2]; i3 = gcsr[e+3];
        i4 = gcsr[e+4]; i5 = gcsr[e+5]; i6 = gcsr[e+6]; i7 = gcsr[e+7];
      }
      uint4 v0 = xq4[(size_t)i0*8 + sl];
      uint4 v1 = xq4[(size_t)i1*8 + sl];
      uint4 v2 = xq4[(size_t)i2*8 + sl];
      uint4 v3 = xq4[(size_t)i3*8 + sl];
      uint4 v4 = xq4[(size_t)i4*8 + sl];
      uint4 v5 = xq4[(size_t)i5*8 + sl];
      uint4 v6 = xq4[(size_t)i6*8 + sl];
      uint4 v7 = xq4[(size_t)i7*8 + sl];
      ACCP16(v0); ACCP16(v1); ACCP16(v2); ACCP16(v3);
      ACCP16(v4); ACCP16(v5); ACCP16(v6); ACCP16(v7);
    }
    for (; e + 4 <= s1; e += 4){
      int i0,i1,i2,i3;
      if (e + 4 <= FUSE_CAP){
        i0 = scsr[e]; i1 = scsr[e+1]; i2 = scsr[e+2]; i3 = scsr[e+3];
      } else {
        i0 = gcsr[e]; i1 = gcsr[e+1]; i2 = gcsr[e+2]; i3 = gcsr[e+3];
      }
      uint4 v0 = xq4[(size_t)i0*8 + sl];
      uint4 v1 = xq4[(size_t)i1*8 + sl];
      uint4 v2 = xq4[(size_t)i2*8 + sl];
      uint4 v3 = xq4[(size_t)i3*8 + sl];
      ACCP16(v0); ACCP16(v1); ACCP16(v2); ACCP16(v3);
    }
    for (; e < s1; e++){
      int ii = (e < FUSE_CAP) ? scsr[e] : gcsr[e];
      uint4 v = xq4[(size_t)ii*8 + sl];
      ACCP16(v);
    }
    int d = s1 - s0;
    float inv = 1.0f / (float)(d > 0 ? d : 1);
    uint4 o0, o1;
    o0.x = pack2(b0.x*inv, b0.y*inv);  o0.y = pack2(b1.x*inv, b1.y*inv);
    o0.z = pack2(b2.x*inv, b2.y*inv);  o0.w = pack2(b3.x*inv, b3.y*inv);
    o1.x = pack2(b4.x*inv, b4.y*inv);  o1.y = pack2(b5.x*inv, b5.y*inv);
    o1.z = pack2(b6.x*inv, b6.y*inv);  o1.w = pack2(b7.x*inv, b7.y*inv);
    Ms4[rk*17 + sl*2]     = o0;
    Ms4[rk*17 + sl*2 + 1] = o1;
  }
  __syncthreads();

  int quad = lane >> 4, c = lane & 15;
  int woff = w*16;
  int r0 = n0 + woff + c;
  const unsigned short* Ag = (const unsigned short*)A.xb;
  f32x4 acc[8];
  #pragma unroll
  for (int nt=0;nt<8;nt++) acc[nt] = (f32x4){0.f,0.f,0.f,0.f};
  #pragma unroll
  for (int kk=0; kk<8; kk++){
    int ka = (kk & 3)*32 + quad*8;
    short8 a0;
    if (kk < 4){
      a0 = *(const short8*)&Ms[(woff + c)*136 + ka];
    } else {
      a0 = (short8){0,0,0,0,0,0,0,0};
      if (r0 < A.N) a0 = *(const short8*)(Ag + (size_t)r0*128 + ka);
    }
    #pragma unroll
    for (int nt=0; nt<8; nt++){
      short8 bb2 = *(const short8*)(A.Bpk0 + (size_t)((kk*8 + nt)*64 + lane)*8);
      acc[nt] = __builtin_amdgcn_mfma_f32_16x16x32_bf16(a0, bb2, acc[nt], 0, 0, 0);
    }
  }
  float scv[8], shv[8];
  #pragma unroll
  for (int nt=0;nt<8;nt++){ scv[nt] = A.sc0[nt*16 + c]; shv[nt] = A.sh0[nt*16 + c]; }
  #pragma unroll
  for (int r=0;r<4;r++){
    int row = n0 + woff + quad*4 + r;
    if (row < A.N){
      float u[8];
      #pragma unroll
      for (int nt=0;nt<8;nt++){
        float uu = acc[nt][r]*scv[nt] + shv[nt];
        u[nt] = fmaxf(uu, 0.f);
        A.h_a[(size_t)row*128 + nt*16 + c] = f2bf(u[nt]);
      }
      uint2 q;
      q.x = pk_fp8x4(u[0], u[1], u[2], u[3]);
      q.y = pk_fp8x4(u[4], u[5], u[6], u[7]);
      ((uint2*)A.haq)[(size_t)row*16 + c] = q;
    }
  }
}

// ---------------- P3: fused layer-1 (gather haq + GEMM1 + yl mini-GEMM), 64-node items ----------------

static __device__ void p3_fuse1(int wb, uint4* pool4, const MegaArgs& A){
  uint4* Ms4  = pool4;                 // 1088 u4
  uint4* sBL4 = pool4 + 1088;          // 1024 u4
  int* sw     = (int*)(pool4 + 2112);  // 2 ints
  unsigned short* Ms = (unsigned short*)Ms4;
  int* scsr = (int*)sBL4;
  int t = threadIdx.x;
  __syncthreads();
  int n0 = wb*64;
  if (t < 2) sw[t] = A.off[min(n0 + t*64, A.N)];
  __syncthreads();
  int e0b = sw[0];
  int span = sw[1] - e0b;
  for (int i = t; i < span && i < CAPL; i += 256) scsr[i] = A.csr[e0b + i];
  __syncthreads();

  int lane = t & 63, w = t >> 6;
  int sl = lane & 7;
  const uint4* hq4 = (const uint4*)A.haq;

  #pragma unroll
  for (int it=0; it<2; it++){
    int rk = w*16 + it*8 + (lane >> 3);
    int idx = n0 + rk;
    bool valid = idx < A.N;
    int s0 = valid ? A.off[idx]   : 0;
    int s1 = valid ? A.off[idx+1] : 0;
    f32x2 b0={0,0},b1={0,0},b2={0,0},b3={0,0},b4={0,0},b5={0,0},b6={0,0},b7={0,0};
    int e = s0;
    for (; e + 8 <= s1; e += 8){
      int le = e - e0b;
      int i0,i1,i2,i3,i4,i5,i6,i7;
      if (le + 8 <= CAPL){
        i0 = scsr[le];   i1 = scsr[le+1]; i2 = scsr[le+2]; i3 = scsr[le+3];
        i4 = scsr[le+4]; i5 = scsr[le+5]; i6 = scsr[le+6]; i7 = scsr[le+7];
      } else {
        i0 = A.csr[e];   i1 = A.csr[e+1]; i2 = A.csr[e+2]; i3 = A.csr[e+3];
        i4 = A.csr[e+4]; i5 = A.csr[e+5]; i6 = A.csr[e+6]; i7 = A.csr[e+7];
      }
      uint4 v0 = hq4[(size_t)i0*8 + sl];
      uint4 v1 = hq4[(size_t)i1*8 + sl];
      uint4 v2 = hq4[(size_t)i2*8 + sl];
      uint4 v3 = hq4[(size_t)i3*8 + sl];
      uint4 v4 = hq4[(size_t)i4*8 + sl];
      uint4 v5 = hq4[(size_t)i5*8 + sl];
      uint4 v6 = hq4[(size_t)i6*8 + sl];
      uint4 v7 = hq4[(size_t)i7*8 + sl];
      ACCP16(v0); ACCP16(v1); ACCP16(v2); ACCP16(v3);
      ACCP16(v4); ACCP16(v5); ACCP16(v6); ACCP16(v7);
    }
    for (; e + 4 <= s1; e += 4){
      int le = e - e0b;
      int i0,i1,i2,i3;
      if (le + 4 <= CAPL){
        i0 = scsr[le]; i1 = scsr[le+1]; i2 = scsr[le+2]; i3 = scsr[le+3];
      } else {
        i0 = A.csr[e]; i1 = A.csr[e+1]; i2 = A.csr[e+2]; i3 = A.csr[e+3];
      }
      uint4 v0 = hq4[(size_t)i0*8 + sl];
      uint4 v1 = hq4[(size_t)i1*8 + sl];
      uint4 v2 = hq4[(size_t)i2*8 + sl];
      uint4 v3 = hq4[(size_t)i3*8 + sl];
      ACCP16(v0); ACCP16(v1); ACCP16(v2); ACCP16(v3);
    }
    for (; e < s1; e++){
      int le = e - e0b;
      int ii = (le < CAPL) ? scsr[le] : A.csr[e];
      uint4 v = hq4[(size_t)ii*8 + sl];
      ACCP16(v);
    }
    int d = s1 - s0;
    float inv = 1.0f / (float)(d > 0 ? d : 1);
    uint4 o0, o1;
    o0.x = pack2(b0.x*inv, b0.y*inv);  o0.y = pack2(b1.x*inv, b1.y*inv);
    o0.z = pack2(b2.x*inv, b2.y*inv);  o0.w = pack2(b3.x*inv, b3.y*inv);
    o1.x = pack2(b4.x*inv, b4.y*inv);  o1.y = pack2(b5.x*inv, b5.y*inv);
    o1.z = pack2(b6.x*inv, b6.y*inv);  o1.w = pack2(b7.x*inv, b7.y*inv);
    Ms4[rk*17 + sl*2]     = o0;
    Ms4[rk*17 + sl*2 + 1] = o1;
  }
  __syncthreads();

  int quad = lane >> 4, c = lane & 15;
  int woff = w*16;
  int r0 = n0 + woff + c;
  f32x4 acc[8];
  #pragma unroll
  for (int nt=0;nt<8;nt++) acc[nt] = (f32x4){0.f,0.f,0.f,0.f};
  #pragma unroll
  for (int kk=0; kk<8; kk++){
    int ka = (kk & 3)*32 + quad*8;
    short8 a0;
    if (kk < 4){
      a0 = *(const short8*)&Ms[(woff + c)*136 + ka];
    } else {
      a0 = (short8){0,0,0,0,0,0,0,0};
      if (r0 < A.N) a0 = *(const short8*)(A.h_a + (size_t)r0*128 + ka);
    }
    #pragma unroll
    for (int nt=0; nt<8; nt++){
      short8 bb2 = *(const short8*)(A.Bpk1 + (size_t)((kk*8 + nt)*64 + lane)*8);
      acc[nt] = __builtin_amdgcn_mfma_f32_16x16x32_bf16(a0, bb2, acc[nt], 0, 0, 0);
    }
  }
  float scv[8], shv[8];
  #pragma unroll
  for (int nt=0;nt<8;nt++){ scv[nt] = A.sc1[nt*16 + c]; shv[nt] = A.sh1[nt*16 + c]; }
  __syncthreads();
  #pragma unroll
  for (int r=0;r<4;r++){
    int lrow = woff + quad*4 + r;
    int row = n0 + lrow;
    if (row < A.N){
      float u[8];
      #pragma unroll
      for (int nt=0;nt<8;nt++){
        float uu = acc[nt][r]*scv[nt] + shv[nt];
        u[nt] = fmaxf(uu, 0.f);
        A.h_b[(size_t)row*128 + nt*16 + c] = f2bf(u[nt]);
      }
      #pragma unroll
      for (int nt=0;nt<8;nt++) Ms[lrow*136 + nt*16 + c] = f2bf(u[nt]);
    } else {
      #pragma unroll
      for (int nt=0;nt<8;nt++) Ms[lrow*136 + nt*16 + c] = 0;
    }
  }
  {
    const uint4* sL = (const uint4*)A.BpkL;
    #pragma unroll
    for (int i=0;i<4;i++) sBL4[i*256 + t] = sL[i*256 + t];
  }
  __syncthreads();
  unsigned short* BsL = (unsigned short*)sBL4;
  f32x4 acc2[4];
  #pragma unroll
  for (int nt=0;nt<4;nt++) acc2[nt] = (f32x4){0.f,0.f,0.f,0.f};
  int r0l = woff + c;
  #pragma unroll
  for (int kk=0; kk<4; kk++){
    int ka = kk*32 + quad*8;
    short8 a0 = *(const short8*)&Ms[r0l*136 + ka];
    #pragma unroll
    for (int nt=0; nt<4; nt++){
      short8 bb2 = *(const short8*)&BsL[(size_t)((kk*4 + nt)*64 + lane)*8];
      acc2[nt] = __builtin_amdgcn_mfma_f32_16x16x32_bf16(a0, bb2, acc2[nt], 0, 0, 0);
    }
  }
  #pragma unroll
  for (int r=0;r<4;r++){
    int row = n0 + woff + quad*4 + r;
    if (row < A.N){
      unsigned q = pk_fp8x4(acc2[0][r], acc2[1][r], acc2[2][r], acc2[3][r]);
      A.ylb[(size_t)row*16 + c] = q;
    }
  }
}

// ---------------- P4: fused layer-2 (gather ylb + GEMM + BN + L2norm), 64-node items ----------------

static __device__ void p4_aggf(int wb, uint4* pool4, const MegaArgs& A){
  unsigned short* Ms = (unsigned short*)pool4;          // 8 KB
  unsigned short* Bs = (unsigned short*)(pool4 + 512);  // 16 KB
  int* scsr = (int*)(pool4 + 1536);                     // 8 KB
  int* sw   = (int*)(pool4 + 2048);
  int t = threadIdx.x;
  __syncthreads();
  int n0 = wb*64;
  if (t < 2) sw[t] = A.off[min(n0 + t*64, A.N)];
  {
    const uint4* s = (const uint4*)A.BpkR;
    uint4* d = (uint4*)Bs;
    #pragma unroll
    for (int i=0;i<4;i++) d[i*256 + t] = s[i*256 + t];
  }
  __syncthreads();
  int e0b = sw[0];
  int span = sw[1] - e0b;
  for (int i = t; i < span && i < AGGF_CAP; i += 256) scsr[i] = A.csr[e0b + i];
  __syncthreads();

  int lane = t & 63, w = t >> 6;
  int sl4 = lane & 3;
  const uint4* ylq4 = (const uint4*)A.ylb;

  {
    int rk = w*16 + (lane >> 2);
    int idx = n0 + rk;
    bool valid = idx < A.N;
    int s0 = valid ? A.off[idx]   : 0;
    int s1 = valid ? A.off[idx+1] : 0;
    f32x2 b0={0,0},b1={0,0},b2={0,0},b3={0,0},b4={0,0},b5={0,0},b6={0,0},b7={0,0};
    int e = s0;
    for (; e + 8 <= s1; e += 8){
      int le = e - e0b;
      int i0,i1,i2,i3,i4,i5,i6,i7;
      if (le + 8 <= AGGF_CAP){
        i0 = scsr[le];   i1 = scsr[le+1]; i2 = scsr[le+2]; i3 = scsr[le+3];
        i4 = scsr[le+4]; i5 = scsr[le+5]; i6 = scsr[le+6]; i7 = scsr[le+7];
      } else {
        i0 = A.csr[e];   i1 = A.csr[e+1]; i2 = A.csr[e+2]; i3 = A.csr[e+3];
        i4 = A.csr[e+4]; i5 = A.csr[e+5]; i6 = A.csr[e+6]; i7 = A.csr[e+7];
      }
      uint4 v0 = ylq4[(size_t)i0*4 + sl4];
      uint4 v1 = ylq4[(size_t)i1*4 + sl4];
      uint4 v2 = ylq4[(size_t)i2*4 + sl4];
      uint4 v3 = ylq4[(size_t)i3*4 + sl4];
      uint4 v4 = ylq4[(size_t)i4*4 + sl4];
      uint4 v5 = ylq4[(size_t)i5*4 + sl4];
      uint4 v6 = ylq4[(size_t)i6*4 + sl4];
      uint4 v7 = ylq4[(size_t)i7*4 + sl4];
      ACCP16(v0); ACCP16(v1); ACCP16(v2); ACCP16(v3);
      ACCP16(v4); ACCP16(v5); ACCP16(v6); ACCP16(v7);
    }
    for (; e + 4 <= s1; e += 4){
      int le = e - e0b;
      int i0,i1,i2,i3;
      if (le + 4 <= AGGF_CAP){
        i0 = scsr[le]; i1 = scsr[le+1]; i2 = scsr[le+2]; i3 = scsr[le+3];
      } else {
        i0 = A.csr[e]; i1 = A.csr[e+1]; i2 = A.csr[e+2]; i3 = A.csr[e+3];
      }
      uint4 v0 = ylq4[(size_t)i0*4 + sl4];
      uint4 v1 = ylq4[(size_t)i1*4 + sl4];
      uint4 v2 = ylq4[(size_t)i2*4 + sl4];
      uint4 v3 = ylq4[(size_t)i3*4 + sl4];
      ACCP16(v0); ACCP16(v1); ACCP16(v2); ACCP16(v3);
    }
    for (; e < s1; e++){
      int le = e - e0b;
      int ii = (le < AGGF_CAP) ? scsr[le] : A.csr[e];
      uint4 v = ylq4[(size_t)ii*4 + sl4];
      ACCP16(v);
    }
    int d = s1 - s0;
    float inv = 1.0f / (float)(d > 0 ? d : 1);
    uint4 o0, o1;
    o0.x = pack2(b0.x*inv, b0.y*inv);  o0.y = pack2(b1.x*inv, b1.y*inv);
    o0.z = pack2(b2.x*inv, b2.y*inv);  o0.w = pack2(b3.x*inv, b3.y*inv);
    o1.x = pack2(b4.x*inv, b4.y*inv);  o1.y = pack2(b5.x*inv, b5.y*inv);
    o1.z = pack2(b6.x*inv, b6.y*inv);  o1.w = pack2(b7.x*inv, b7.y*inv);
    ((uint4*)Ms)[rk*8 + sl4*2]     = o0;
    ((uint4*)Ms)[rk*8 + sl4*2 + 1] = o1;
  }
  __syncthreads();

  int quad = lane >> 4, c = lane & 15;
  int woff = w*16;
  int r0 = n0 + woff + c;
  f32x4 acc[4];
  #pragma unroll
  for (int nt=0;nt<4;nt++) acc[nt] = (f32x4){0.f,0.f,0.f,0.f};
  #pragma unroll
  for (int kk=0; kk<4; kk++){
    int ka = kk*32 + quad*8;
    short8 a0 = {0,0,0,0,0,0,0,0};
    if (r0 < A.N) a0 = *(const short8*)(A.h_b + (size_t)r0*128 + ka);
    #pragma unroll
    for (int nt=0; nt<4; nt++){
      short8 bb2 = *(const short8*)&Bs[(size_t)((kk*4 + nt)*64 + lane)*8];
      acc[nt] = __builtin_amdgcn_mfma_f32_16x16x32_bf16(a0, bb2, acc[nt], 0, 0, 0);
    }
  }
  float scv[4], shv[4];
  #pragma unroll
  for (int nt=0;nt<4;nt++){ scv[nt] = A.sc2[nt*16 + c]; shv[nt] = A.sh2[nt*16 + c]; }
  #pragma unroll
  for (int r=0;r<4;r++){
    int lr = woff + quad*4 + r;
    int row = n0 + lr;
    float v[4];
    float ss2 = 0.f;
    if (row < A.N){
      #pragma unroll
      for (int nt=0;nt<4;nt++){
        float u = acc[nt][r] + bf2f(Ms[lr*64 + c*4 + nt]);
        u = u*scv[nt] + shv[nt];
        v[nt] = u;
        ss2 += u*u;
      }
    } else {
      #pragma unroll
      for (int nt=0;nt<4;nt++) v[nt] = 0.f;
    }
    ss2 += __shfl_xor(ss2, 1, 64);
    ss2 += __shfl_xor(ss2, 2, 64);
    ss2 += __shfl_xor(ss2, 4, 64);
    ss2 += __shfl_xor(ss2, 8, 64);
    float rn = 1.0f / fmaxf(sqrtf(ss2), 1e-12f);
    if (row < A.N){
      #pragma unroll
      for (int nt=0;nt<4;nt++) A.outf[(size_t)row*64 + nt*16 + c] = v[nt]*rn;
    }
  }
}

// ---------------- the mega kernel ----------------

__global__ __launch_bounds__(256, 2) void k_mega(MegaArgs A){
  __shared__ uint4 pool4[2120];   // 33920 B, reused per phase
  for (int wb = blockIdx.x; wb < A.p0Total; wb += gridDim.x) p0_prep(wb, pool4, A);
  gbar(A.barCnt, A.barEpoch, A.nblk, 1);
  for (int wb = blockIdx.x; wb < A.aBlocks; wb += gridDim.x) p1_bucketA(wb, pool4, A);
  gbar(A.barCnt, A.barEpoch, A.nblk, 2);
  for (int wb = blockIdx.x; wb < A.nb2; wb += gridDim.x) p2_bfuse(wb, pool4, A);
  gbar(A.barCnt, A.barEpoch, A.nblk, 3);
  for (int wb = blockIdx.x; wb < A.nb2; wb += gridDim.x) p3_fuse1(wb, pool4, A);
  gbar(A.barCnt, A.barEpoch, A.nblk, 4);
  for (int wb = blockIdx.x; wb < A.nb2; wb += gridDim.x) p4_aggf(wb, pool4, A);
}

// ---------------- launcher ----------------

extern "C" void kernel_launch(void* const* d_in, const int* in_sizes, int n_in,
                              void* d_out, int out_size, void* d_ws, size_t ws_size,
                              hipStream_t stream){
  const float* x = (const float*)d_in[0];
  const int* ei  = (const int*)d_in[1];
  int N = in_sizes[0] / 128;
  int E = in_sizes[1] / 2;
  const int* esrc = ei;
  const int* edst = ei + E;
  int nbuck = CDIV(N, 128);
  int nb2 = 2*nbuck;

  const float *Wl[3], *bl[3], *Wr[3], *g[3], *bb[3], *rm[3], *rv[3];
  int dout[3];
  for (int i=0;i<3;i++){
    int base = 2 + 7*i;
    Wl[i]=(const float*)d_in[base];   bl[i]=(const float*)d_in[base+1];
    Wr[i]=(const float*)d_in[base+2]; g[i] =(const float*)d_in[base+3];
    bb[i]=(const float*)d_in[base+4]; rm[i]=(const float*)d_in[base+5];
    rv[i]=(const float*)d_in[base+6];
    dout[i] = in_sizes[base] / 128;
  }

  char* p = (char*)d_ws;
  size_t o = 0;
  auto alloc = [&](size_t bytes)->void*{ void* r = p + o; o += (bytes + 255) & ~(size_t)255; return r; };
  int* bz    = (int*)alloc((size_t)(2*nbuck + 2)*4);   // bcnt | bcur | barCnt | barEpoch
  int* bcnt  = bz;
  int* bcur  = bz + nbuck;
  int* barCnt   = bz + 2*nbuck;
  int* barEpoch = bz + 2*nbuck + 1;
  int* off   = (int*)alloc((size_t)(N+1)*4);
  int* csr   = (int*)alloc((size_t)E*4);
  unsigned* ebuf = (unsigned*)alloc((size_t)E*4);
  unsigned* xb   = (unsigned*)alloc((size_t)N*64*4);   // bf16 x (natural)
  unsigned* xq   = (unsigned*)alloc((size_t)N*128);    // fp8 x (identity order)
  unsigned* h_a  = (unsigned*)alloc((size_t)N*64*4);   // bf16 h1 (natural)
  unsigned* haq  = (unsigned*)alloc((size_t)N*128);    // fp8 h1 (perm)
  unsigned* h_b  = (unsigned*)alloc((size_t)N*64*4);   // bf16 h2 (natural)
  unsigned* ylb  = (unsigned*)alloc((size_t)N*64);     // fp8 yl (perm2)
  unsigned short* Bpk01[2];
  float* sc[3]; float* sh[3];
  for (int i=0;i<2;i++) Bpk01[i] = (unsigned short*)alloc((size_t)256*dout[i]*2);
  unsigned short* BpkL = (unsigned short*)alloc((size_t)128*dout[2]*2);
  unsigned short* BpkR = (unsigned short*)alloc((size_t)128*dout[2]*2);
  for (int i=0;i<3;i++){
    sc[i] = (float*)alloc((size_t)dout[i]*4);
    sh[i] = (float*)alloc((size_t)dout[i]*4);
  }

  hipMemsetAsync(bz, 0, (size_t)(2*nbuck + 2)*4, stream);

  MegaArgs ma;
  ma.x = x; ma.n4 = N*32;
  ma.xb = xb; ma.xq = xq;
  ma.esrc = esrc; ma.edst = edst;
  ma.E = E; ma.N = N; ma.nbuck = nbuck;
  ma.bcnt = bcnt; ma.bcur = bcur;
  ma.barCnt = barCnt; ma.barEpoch = barEpoch;
  ma.off = off; ma.csr = csr; ma.ebuf = ebuf;
  ma.Bpk0 = Bpk01[0]; ma.Bpk1 = Bpk01[1]; ma.BpkL = BpkL; ma.BpkR = BpkR;
  ma.sc0 = sc[0]; ma.sh0 = sh[0]; ma.sc1 = sc[1]; ma.sh1 = sh[1]; ma.sc2 = sc[2]; ma.sh2 = sh[2];
  ma.h_a = (unsigned short*)h_a; ma.h_b = (unsigned short*)h_b;
  ma.haq = haq; ma.ylb = ylb;
  ma.outf = (float*)d_out;
  ma.wa0 = { Wl[0], Wr[0], bl[0], g[0], bb[0], rm[0], rv[0], Bpk01[0], sc[0], sh[0], 8, dout[0], 1, CDIV(256*dout[0]+dout[0],256), 0 };
  ma.wa1 = { Wl[1], Wr[1], bl[1], g[1], bb[1], rm[1], rv[1], Bpk01[1], sc[1], sh[1], 8, dout[1], 1, CDIV(256*dout[1]+dout[1],256), 1 };
  ma.wa2 = { Wl[2], nullptr, nullptr, nullptr, nullptr, nullptr, nullptr, BpkL, nullptr, nullptr, 4, dout[2], 0, CDIV(128*dout[2],256), 0 };
  ma.wa3 = { Wr[2], nullptr, bl[2], g[2], bb[2], rm[2], rv[2], BpkR, sc[2], sh[2], 4, dout[2], 1, CDIV(128*dout[2]+dout[2],256), 0 };
  ma.castBlocks = CDIV(N*32, 256);
  ma.histBlocks = CDIV(E, 256*16);
  ma.p0Total = ma.castBlocks + ma.histBlocks + ma.wa0.nblk + ma.wa1.nblk + ma.wa2.nblk + ma.wa3.nblk;
  ma.aBlocks = CDIV(E, 256*8);
  ma.nb2 = nb2;

  static int g_grid = 0;
  if (g_grid == 0){
    int perCU = 0, cus = 0;
    if (hipOccupancyMaxActiveBlocksPerMultiprocessor(&perCU, k_mega, 256, 0) != hipSuccess || perCU < 1) perCU = 2;
    if (hipDeviceGetAttribute(&cus, hipDeviceAttributeMultiprocessorCount, 0) != hipSuccess || cus < 1) cus = 256;
    g_grid = perCU * cus;
  }
  ma.nblk = g_grid;

  k_mega<<<g_grid, 256, 0, stream>>>(ma);
}

// Round 8
// 216.745 us; speedup vs baseline: 3.0411x; 3.0411x over previous
//
#include <hip/hip_runtime.h>
#include <hip/hip_bf16.h>

#define CDIV(a,b) (((a)+(b)-1)/(b))
#define NBUCK_MAX 512   // 128-node ebuf buckets; supports N up to 65536 (ebuf packing needs N<=65536)
#define BUCK_CAP 3072   // fixed slots per 128-node bucket (mean 2046, +23 sigma; overflow list past that)
#define FUSE_CAP 1536   // staged csr entries per 64-node bfuse block (mean 1024)
#define CAPL     4096   // fuse1 csr window (fills the 16KB sBL4 region)
#define AGGF_CAP 2048   // aggf csr window

typedef __attribute__((ext_vector_type(8))) short short8;
typedef __attribute__((ext_vector_type(4))) float f32x4;
typedef __attribute__((ext_vector_type(2))) float f32x2;

static __device__ __forceinline__ unsigned short f2bf(float f){
  union { float f; unsigned u; } v; v.f = f;
  unsigned r = v.u + 0x7fffu + ((v.u >> 16) & 1u);   // RNE
  return (unsigned short)(r >> 16);
}
static __device__ __forceinline__ unsigned pack2(float lo, float hi){
  return (unsigned)f2bf(lo) | ((unsigned)f2bf(hi) << 16);
}
static __device__ __forceinline__ float bf2f(unsigned short s){
  union { unsigned u; float f; } v; v.u = ((unsigned)s) << 16; return v.f;
}
// pack 4 f32 -> 4 fp8 e4m3 bytes (byte0=a .. byte3=d)
static __device__ __forceinline__ unsigned pk_fp8x4(float a, float b, float c, float d){
  int v = __builtin_amdgcn_cvt_pk_fp8_f32(a, b, 0, false);
  v = __builtin_amdgcn_cvt_pk_fp8_f32(c, d, v, true);
  return (unsigned)v;
}

// accumulate 16 fp8 bytes (uint4) into f32x2 accumulators b0..b7 (v_pk_add_f32 path)
#define ACCP16(v) { b0 += __builtin_amdgcn_cvt_pk_f32_fp8((int)v.x, false); \
                    b1 += __builtin_amdgcn_cvt_pk_f32_fp8((int)v.x, true);  \
                    b2 += __builtin_amdgcn_cvt_pk_f32_fp8((int)v.y, false); \
                    b3 += __builtin_amdgcn_cvt_pk_f32_fp8((int)v.y, true);  \
                    b4 += __builtin_amdgcn_cvt_pk_f32_fp8((int)v.z, false); \
                    b5 += __builtin_amdgcn_cvt_pk_f32_fp8((int)v.z, true);  \
                    b6 += __builtin_amdgcn_cvt_pk_f32_fp8((int)v.w, false); \
                    b7 += __builtin_amdgcn_cvt_pk_f32_fp8((int)v.w, true); }

// ---------------- weight pack args ----------------
// perm: first-128 K positions hold channel pi(k) = (k&7)*16 + (k>>3) (matches gemm-epilogue fp8 row layout)

struct WtpArgs {
  const float *W0, *W1, *bl, *g, *b, *rm, *rv;
  unsigned short* Bpk; float *sc; float *sh;
  int kblk, dout, do_bn, nblk, perm;
};

static __device__ __forceinline__ void wtp_one(const WtpArgs& a, int idx){
  int NB16 = a.kblk*32*a.dout;
  if (idx < NB16){
    int j = idx & 7, lane = (idx >> 3) & 63, rest = idx >> 9;
    int NT = a.dout >> 4;
    int nt = rest % NT, kk = rest / NT;
    int nn = nt*16 + (lane & 15);
    int k  = kk*32 + ((lane >> 4) * 8) + j;
    float v;
    if (k < 128){
      int kc = a.perm ? (((k & 7) << 4) | (k >> 3)) : k;
      v = a.W0[nn*128 + kc];
    } else {
      v = a.W1[nn*128 + (k - 128)];
    }
    a.Bpk[idx] = f2bf(v);
  } else if (a.do_bn && idx < NB16 + a.dout){
    int jj = idx - NB16;
    float s = a.g[jj] * rsqrtf(a.rv[jj] + 1e-5f);
    a.sc[jj] = s;
    a.sh[jj] = (a.bl[jj] - a.rm[jj]) * s + a.b[jj];
  }
}

// ---------------- k_prep: cast x->bf16+fp8 | edge binning into fixed-cap buckets | weight pack ----------------
// Binning: per-block LDS count -> one global atomicAdd(bcur[b]) reservation per bucket -> scatter.
// Slot >= BUCK_CAP goes to the overflow list (statistically never for Poisson(2046) buckets).

__global__ __launch_bounds__(256) void k_prep(const float* __restrict__ x, int n4, unsigned* __restrict__ xb,
                                              unsigned* __restrict__ xq,
                                              const int* __restrict__ esrc, const int* __restrict__ edst,
                                              int E, int* __restrict__ bcur, int* __restrict__ ovCnt,
                                              unsigned* __restrict__ ebuf, unsigned* __restrict__ ovBuf,
                                              int nbuck, int castBlocks, int binBlocks,
                                              WtpArgs a0, WtpArgs a1, WtpArgs a2, WtpArgs a3){
  __shared__ int scnt[NBUCK_MAX];
  __shared__ int sbase[NBUCK_MAX];
  int b = blockIdx.x, t = threadIdx.x;
  if (b < castBlocks){
    int i = b*256 + t;            // i over groups of 4 floats
    if (i < n4){
      float4 v = ((const float4*)x)[i];
      uint2 o; o.x = pack2(v.x, v.y); o.y = pack2(v.z, v.w);
      ((uint2*)xb)[i] = o;
      xq[i] = pk_fp8x4(v.x, v.y, v.z, v.w);    // identity channel order
    }
    return;
  }
  b -= castBlocks;
  if (b < binBlocks){
    for (int i=t;i<nbuck;i+=256) scnt[i] = 0;
    __syncthreads();
    constexpr int EPT = 16;
    int e0 = b*256*EPT;
    int bb[EPT]; unsigned pk[EPT];
    #pragma unroll
    for (int i=0;i<EPT;i++){
      int e = e0 + i*256 + t;
      if (e < E){
        int d = edst[e];
        bb[i] = d >> 7;
        pk[i] = ((unsigned)(d & 127) << 16) | (unsigned)esrc[e];
        atomicAdd(&scnt[bb[i]], 1);
      } else bb[i] = -1;
    }
    __syncthreads();
    for (int i=t;i<nbuck;i+=256){
      int c = scnt[i];
      sbase[i] = (c > 0) ? atomicAdd(&bcur[i], c) : 0;
      scnt[i] = 0;
    }
    __syncthreads();
    #pragma unroll
    for (int i=0;i<EPT;i++){
      if (bb[i] >= 0){
        int p = atomicAdd(&scnt[bb[i]], 1);
        int gpos = sbase[bb[i]] + p;
        if (gpos < BUCK_CAP) ebuf[(size_t)bb[i]*BUCK_CAP + gpos] = pk[i];
        else { int oi = atomicAdd(ovCnt, 1); ovBuf[oi] = ((unsigned)bb[i] << 23) | pk[i]; }
      }
    }
    return;
  }
  b -= binBlocks;
  if (b < a0.nblk){ wtp_one(a0, b*256 + t); return; }
  b -= a0.nblk;
  if (b < a1.nblk){ wtp_one(a1, b*256 + t); return; }
  b -= a1.nblk;
  if (b < a2.nblk){ wtp_one(a2, b*256 + t); return; }
  b -= a2.nblk;
  wtp_one(a3, b*256 + t);
}

// ---------------- k_bfuse: csr build + fused layer-0, 64-node blocks (two blocks share a 128-node bucket) ----------------
// Static bucket base b*BUCK_CAP: no global scan needed. Writes off[] (padded-absolute) + deg[].

__global__ __launch_bounds__(256, 3) void k_bfuse(
    const unsigned* __restrict__ ebuf, const int* __restrict__ bcur,
    const int* __restrict__ ovCnt, const unsigned* __restrict__ ovBuf, int N,
    int* __restrict__ off, int* __restrict__ deg, int* __restrict__ csr,
    const uint4* __restrict__ xq4, const unsigned short* __restrict__ Ag,
    const unsigned short* __restrict__ Bpk, const float* __restrict__ sc, const float* __restrict__ sh,
    unsigned short* __restrict__ outh, unsigned* __restrict__ outq){
  __shared__ uint4 Ms4[64*17];      // 17408 B mean tile (head reused as sdeg/sabs/cur during csr build)
  __shared__ int scsr[FUSE_CAP];    // 6144 B local csr (this block's 64-node half)
  unsigned short* Ms = (unsigned short*)Ms4;
  int* sdeg = (int*)Ms4;            // [128]
  int* sabs = sdeg + 128;           // [129] window-local offsets
  int* cur  = sabs + 129;           // [128]
  int wb = blockIdx.x;
  int b = wb >> 1, hi = wb & 1;
  int t = threadIdx.x;
  if (t < 128){ sdeg[t] = 0; cur[t] = 0; }
  __syncthreads();
  size_t bBase = (size_t)b*BUCK_CAP;
  int cntMain = min(bcur[b], BUCK_CAP);
  int ov = *ovCnt;
  for (int e = t; e < cntMain; e += 256)
    atomicAdd(&sdeg[ebuf[bBase + e] >> 16], 1);
  for (int i = t; i < ov; i += 256){
    unsigned v = ovBuf[i];
    if ((int)(v >> 23) == b) atomicAdd(&sdeg[(v >> 16) & 127u], 1);
  }
  __syncthreads();
  // scan 128 degrees -> window-local starts sabs[0..128]
  for (int d=1; d<128; d<<=1){
    int u = (t < 128 && t >= d) ? sdeg[t-d] : 0;
    __syncthreads();
    if (t < 128) sdeg[t] += u;
    __syncthreads();
  }
  if (t == 0) sabs[0] = 0;
  if (t < 128) sabs[t+1] = sdeg[t];
  __syncthreads();
  int base64 = sabs[hi*64];
  int myTot  = sabs[hi*64 + 64] - base64;
  int n0 = (b << 7) + hi*64;
  int cnt = (N > n0) ? min(64, N - n0) : 0;
  if (t < cnt){
    off[n0 + t] = (int)bBase + sabs[hi*64 + t];
    deg[n0 + t] = sabs[hi*64 + t + 1] - sabs[hi*64 + t];
  }
  // stash this thread's gather ranges before Ms region is reused
  int lane = t & 63, w = t >> 6, sl = lane & 7;
  int gs0[2], gs1[2];
  #pragma unroll
  for (int it=0; it<2; it++){
    int rk = w*16 + it*8 + (lane >> 3);          // local row 0..63
    gs0[it] = sabs[hi*64 + rk] - base64;
    gs1[it] = sabs[hi*64 + rk + 1] - base64;
  }
  bool fits = myTot <= FUSE_CAP;
  // scatter own-half edges into local csr (LDS if fits, else global)
  for (int e = t; e < cntMain; e += 256){
    unsigned pr = ebuf[bBase + e];
    int ln = (int)(pr >> 16);
    if ((ln >> 6) == hi){
      int p = atomicAdd(&cur[ln], 1);
      int gpos = sabs[ln] + p;                    // position within full window
      int sv = (int)(pr & 0xffffu);
      if (fits) scsr[gpos - base64] = sv;
      else      csr[bBase + gpos] = sv;
    }
  }
  for (int i = t; i < ov; i += 256){
    unsigned v = ovBuf[i];
    if ((int)(v >> 23) == b){
      int ln = (int)((v >> 16) & 127u);
      if ((ln >> 6) == hi){
        int p = atomicAdd(&cur[ln], 1);
        int gpos = sabs[ln] + p;
        int sv = (int)(v & 0xffffu);
        if (fits) scsr[gpos - base64] = sv;
        else      csr[bBase + gpos] = sv;
      }
    }
  }
  __syncthreads();
  const int* gcsr = csr + bBase + base64;
  if (fits){
    for (int i = t; i < myTot; i += 256) csr[bBase + base64 + i] = scsr[i];
  } else {
    for (int i = t; i < FUSE_CAP; i += 256) scsr[i] = gcsr[i];
    __syncthreads();
  }

  // ---- gather phase: 8 lanes x uint4 per node, 16 nodes/wave ----
  #pragma unroll
  for (int it=0; it<2; it++){
    int rk = w*16 + it*8 + (lane >> 3);
    int s0 = gs0[it], s1 = gs1[it];
    f32x2 b0={0,0},b1={0,0},b2={0,0},b3={0,0},b4={0,0},b5={0,0},b6={0,0},b7={0,0};
    int e = s0;
    for (; e + 8 <= s1; e += 8){
      int i0,i1,i2,i3,i4,i5,i6,i7;
      if (e + 8 <= FUSE_CAP){
        i0 = scsr[e];   i1 = scsr[e+1]; i2 = scsr[e+2]; i3 = scsr[e+3];
        i4 = scsr[e+4]; i5 = scsr[e+5]; i6 = scsr[e+6]; i7 = scsr[e+7];
      } else {
        i0 = gcsr[e];   i1 = gcsr[e+1]; i2 = gcsr[e+2]; i3 = gcsr[e+3];
        i4 = gcsr[e+4]; i5 = gcsr[e+5]; i6 = gcsr[e+6]; i7 = gcsr[e+7];
      }
      uint4 v0 = xq4[(size_t)i0*8 + sl];
      uint4 v1 = xq4[(size_t)i1*8 + sl];
      uint4 v2 = xq4[(size_t)i2*8 + sl];
      uint4 v3 = xq4[(size_t)i3*8 + sl];
      uint4 v4 = xq4[(size_t)i4*8 + sl];
      uint4 v5 = xq4[(size_t)i5*8 + sl];
      uint4 v6 = xq4[(size_t)i6*8 + sl];
      uint4 v7 = xq4[(size_t)i7*8 + sl];
      ACCP16(v0); ACCP16(v1); ACCP16(v2); ACCP16(v3);
      ACCP16(v4); ACCP16(v5); ACCP16(v6); ACCP16(v7);
    }
    for (; e + 4 <= s1; e += 4){
      int i0,i1,i2,i3;
      if (e + 4 <= FUSE_CAP){
        i0 = scsr[e]; i1 = scsr[e+1]; i2 = scsr[e+2]; i3 = scsr[e+3];
      } else {
        i0 = gcsr[e]; i1 = gcsr[e+1]; i2 = gcsr[e+2]; i3 = gcsr[e+3];
      }
      uint4 v0 = xq4[(size_t)i0*8 + sl];
      uint4 v1 = xq4[(size_t)i1*8 + sl];
      uint4 v2 = xq4[(size_t)i2*8 + sl];
      uint4 v3 = xq4[(size_t)i3*8 + sl];
      ACCP16(v0); ACCP16(v1); ACCP16(v2); ACCP16(v3);
    }
    for (; e < s1; e++){
      int ii = (e < FUSE_CAP) ? scsr[e] : gcsr[e];
      uint4 v = xq4[(size_t)ii*8 + sl];
      ACCP16(v);
    }
    int d = s1 - s0;
    float inv = 1.0f / (float)(d > 0 ? d : 1);
    uint4 o0, o1;
    o0.x = pack2(b0.x*inv, b0.y*inv);  o0.y = pack2(b1.x*inv, b1.y*inv);
    o0.z = pack2(b2.x*inv, b2.y*inv);  o0.w = pack2(b3.x*inv, b3.y*inv);
    o1.x = pack2(b4.x*inv, b4.y*inv);  o1.y = pack2(b5.x*inv, b5.y*inv);
    o1.z = pack2(b6.x*inv, b6.y*inv);  o1.w = pack2(b7.x*inv, b7.y*inv);
    Ms4[rk*17 + sl*2]     = o0;
    Ms4[rk*17 + sl*2 + 1] = o1;
  }
  __syncthreads();

  // ---- GEMM phase: C = [mean | Ag] @ B (K=256), BN + ReLU; wave w owns rows [w*16, w*16+16) ----
  int quad = lane >> 4, c = lane & 15;
  int woff = w*16;
  int r0 = n0 + woff + c;

  f32x4 acc[8];
  #pragma unroll
  for (int nt=0;nt<8;nt++) acc[nt] = (f32x4){0.f,0.f,0.f,0.f};

  #pragma unroll
  for (int kk=0; kk<8; kk++){
    int ka = (kk & 3)*32 + quad*8;
    short8 a0;
    if (kk < 4){
      a0 = *(const short8*)&Ms[(woff + c)*136 + ka];
    } else {
      a0 = (short8){0,0,0,0,0,0,0,0};
      if (r0 < N) a0 = *(const short8*)(Ag + (size_t)r0*128 + ka);
    }
    #pragma unroll
    for (int nt=0; nt<8; nt++){
      short8 bb2 = *(const short8*)(Bpk + (size_t)((kk*8 + nt)*64 + lane)*8);
      acc[nt] = __builtin_amdgcn_mfma_f32_16x16x32_bf16(a0, bb2, acc[nt], 0, 0, 0);
    }
  }

  float scv[8], shv[8];
  #pragma unroll
  for (int nt=0;nt<8;nt++){ scv[nt] = sc[nt*16 + c]; shv[nt] = sh[nt*16 + c]; }

  #pragma unroll
  for (int r=0;r<4;r++){
    int row = n0 + woff + quad*4 + r;
    if (row < N){
      float u[8];
      #pragma unroll
      for (int nt=0;nt<8;nt++){
        float uu = acc[nt][r]*scv[nt] + shv[nt];
        u[nt] = fmaxf(uu, 0.f);
        outh[(size_t)row*128 + nt*16 + c] = f2bf(u[nt]);
      }
      // fp8(perm) copy: bytes row*128 + c*8 + j hold channel j*16+c
      uint2 q;
      q.x = pk_fp8x4(u[0], u[1], u[2], u[3]);
      q.y = pk_fp8x4(u[4], u[5], u[6], u[7]);
      ((uint2*)outq)[(size_t)row*16 + c] = q;
    }
  }
}

// ---------------- k_fuse1: fused layer-1 (gather haq + GEMM1 + yl mini-GEMM), 64-node blocks ----------------

__global__ __launch_bounds__(256, 3) void k_fuse1(
    const uint4* __restrict__ hq4, const int* __restrict__ off, const int* __restrict__ deg,
    const int* __restrict__ csr,
    const unsigned short* __restrict__ Ag, const unsigned short* __restrict__ Bpk,
    const float* __restrict__ sc, const float* __restrict__ sh,
    const unsigned short* __restrict__ BpkL,
    unsigned short* __restrict__ outh, unsigned* __restrict__ outyl, int n){
  __shared__ uint4 Ms4[64*17];      // 17408 B
  __shared__ uint4 sBL4[1024];      // 16384 B: csr window (gather) -> BpkL stage (yl phase)
  __shared__ int sw[2];
  unsigned short* Ms = (unsigned short*)Ms4;
  int* scsr = (int*)sBL4;
  int t = threadIdx.x;
  int n0 = blockIdx.x*64;
  if (t == 0){
    sw[0] = off[n0];
    int last = min(n0 + 63, n - 1);
    sw[1] = off[last] + deg[last];
  }
  __syncthreads();
  int e0b = sw[0];
  int span = sw[1] - e0b;
  for (int i = t; i < span && i < CAPL; i += 256) scsr[i] = csr[e0b + i];
  __syncthreads();

  int lane = t & 63, w = t >> 6;
  int sl = lane & 7;

  // ---- gather phase: 16 nodes/wave ----
  #pragma unroll
  for (int it=0; it<2; it++){
    int rk = w*16 + it*8 + (lane >> 3);
    int idx = n0 + rk;
    bool valid = idx < n;
    int s0 = valid ? off[idx] : 0;
    int s1 = valid ? (s0 + deg[idx]) : 0;
    f32x2 b0={0,0},b1={0,0},b2={0,0},b3={0,0},b4={0,0},b5={0,0},b6={0,0},b7={0,0};
    int e = s0;
    for (; e + 8 <= s1; e += 8){
      int le = e - e0b;
      int i0,i1,i2,i3,i4,i5,i6,i7;
      if (le + 8 <= CAPL){
        i0 = scsr[le];   i1 = scsr[le+1]; i2 = scsr[le+2]; i3 = scsr[le+3];
        i4 = scsr[le+4]; i5 = scsr[le+5]; i6 = scsr[le+6]; i7 = scsr[le+7];
      } else {
        i0 = csr[e];   i1 = csr[e+1]; i2 = csr[e+2]; i3 = csr[e+3];
        i4 = csr[e+4]; i5 = csr[e+5]; i6 = csr[e+6]; i7 = csr[e+7];
      }
      uint4 v0 = hq4[(size_t)i0*8 + sl];
      uint4 v1 = hq4[(size_t)i1*8 + sl];
      uint4 v2 = hq4[(size_t)i2*8 + sl];
      uint4 v3 = hq4[(size_t)i3*8 + sl];
      uint4 v4 = hq4[(size_t)i4*8 + sl];
      uint4 v5 = hq4[(size_t)i5*8 + sl];
      uint4 v6 = hq4[(size_t)i6*8 + sl];
      uint4 v7 = hq4[(size_t)i7*8 + sl];
      ACCP16(v0); ACCP16(v1); ACCP16(v2); ACCP16(v3);
      ACCP16(v4); ACCP16(v5); ACCP16(v6); ACCP16(v7);
    }
    for (; e + 4 <= s1; e += 4){
      int le = e - e0b;
      int i0,i1,i2,i3;
      if (le + 4 <= CAPL){
        i0 = scsr[le]; i1 = scsr[le+1]; i2 = scsr[le+2]; i3 = scsr[le+3];
      } else {
        i0 = csr[e]; i1 = csr[e+1]; i2 = csr[e+2]; i3 = csr[e+3];
      }
      uint4 v0 = hq4[(size_t)i0*8 + sl];
      uint4 v1 = hq4[(size_t)i1*8 + sl];
      uint4 v2 = hq4[(size_t)i2*8 + sl];
      uint4 v3 = hq4[(size_t)i3*8 + sl];
      ACCP16(v0); ACCP16(v1); ACCP16(v2); ACCP16(v3);
    }
    for (; e < s1; e++){
      int le = e - e0b;
      int ii = (le < CAPL) ? scsr[le] : csr[e];
      uint4 v = hq4[(size_t)ii*8 + sl];
      ACCP16(v);
    }
    int d = s1 - s0;
    float inv = 1.0f / (float)(d > 0 ? d : 1);
    uint4 o0, o1;
    o0.x = pack2(b0.x*inv, b0.y*inv);  o0.y = pack2(b1.x*inv, b1.y*inv);
    o0.z = pack2(b2.x*inv, b2.y*inv);  o0.w = pack2(b3.x*inv, b3.y*inv);
    o1.x = pack2(b4.x*inv, b4.y*inv);  o1.y = pack2(b5.x*inv, b5.y*inv);
    o1.z = pack2(b6.x*inv, b6.y*inv);  o1.w = pack2(b7.x*inv, b7.y*inv);
    Ms4[rk*17 + sl*2]     = o0;
    Ms4[rk*17 + sl*2 + 1] = o1;
  }
  __syncthreads();

  // ---- GEMM phase: wave w owns rows [w*16, w*16+16) ----
  int quad = lane >> 4, c = lane & 15;
  int woff = w*16;
  int r0 = n0 + woff + c;

  f32x4 acc[8];
  #pragma unroll
  for (int nt=0;nt<8;nt++) acc[nt] = (f32x4){0.f,0.f,0.f,0.f};

  #pragma unroll
  for (int kk=0; kk<8; kk++){
    int ka = (kk & 3)*32 + quad*8;
    short8 a0;
    if (kk < 4){
      a0 = *(const short8*)&Ms[(woff + c)*136 + ka];
    } else {
      a0 = (short8){0,0,0,0,0,0,0,0};
      if (r0 < n) a0 = *(const short8*)(Ag + (size_t)r0*128 + ka);
    }
    #pragma unroll
    for (int nt=0; nt<8; nt++){
      short8 bb2 = *(const short8*)(Bpk + (size_t)((kk*8 + nt)*64 + lane)*8);
      acc[nt] = __builtin_amdgcn_mfma_f32_16x16x32_bf16(a0, bb2, acc[nt], 0, 0, 0);
    }
  }

  float scv[8], shv[8];
  #pragma unroll
  for (int nt=0;nt<8;nt++){ scv[nt] = sc[nt*16 + c]; shv[nt] = sh[nt*16 + c]; }

  __syncthreads();   // all A-reads of Ms done before epilogue overwrites it

  #pragma unroll
  for (int r=0;r<4;r++){
    int lrow = woff + quad*4 + r;
    int row = n0 + lrow;
    if (row < n){
      float u[8];
      #pragma unroll
      for (int nt=0;nt<8;nt++){
        float uu = acc[nt][r]*scv[nt] + shv[nt];
        u[nt] = fmaxf(uu, 0.f);
        outh[(size_t)row*128 + nt*16 + c] = f2bf(u[nt]);
      }
      #pragma unroll
      for (int nt=0;nt<8;nt++) Ms[lrow*136 + nt*16 + c] = f2bf(u[nt]);
    } else {
      #pragma unroll
      for (int nt=0;nt<8;nt++) Ms[lrow*136 + nt*16 + c] = 0;
    }
  }

  // stage BpkL (128x64 bf16 = 1024 uint4) into the csr-window region
  {
    const uint4* sL = (const uint4*)BpkL;
    #pragma unroll
    for (int i=0;i<4;i++) sBL4[i*256 + t] = sL[i*256 + t];
  }
  __syncthreads();
  unsigned short* BsL = (unsigned short*)sBL4;
  f32x4 acc2[4];
  #pragma unroll
  for (int nt=0;nt<4;nt++) acc2[nt] = (f32x4){0.f,0.f,0.f,0.f};
  int r0l = woff + c;
  #pragma unroll
  for (int kk=0; kk<4; kk++){
    int ka = kk*32 + quad*8;
    short8 a0 = *(const short8*)&Ms[r0l*136 + ka];
    #pragma unroll
    for (int nt=0; nt<4; nt++){
      short8 bb2 = *(const short8*)&BsL[(size_t)((kk*4 + nt)*64 + lane)*8];
      acc2[nt] = __builtin_amdgcn_mfma_f32_16x16x32_bf16(a0, bb2, acc2[nt], 0, 0, 0);
    }
  }
  #pragma unroll
  for (int r=0;r<4;r++){
    int row = n0 + woff + quad*4 + r;
    if (row < n){
      // fp8(perm2): byte row*64 + c*4 + nt holds channel nt*16+c
      unsigned q = pk_fp8x4(acc2[0][r], acc2[1][r], acc2[2][r], acc2[3][r]);
      outyl[(size_t)row*16 + c] = q;
    }
  }
}

// ---------------- fused layer-3: mean-yl gather (64-dim fp8) + GEMM (h_b@Wr2^T) + BN + L2norm, 64-node blocks ----------------

__global__ __launch_bounds__(256, 3) void k_aggf(
    const uint4* __restrict__ ylq4, const int* __restrict__ off, const int* __restrict__ deg,
    const int* __restrict__ csr,
    const unsigned short* __restrict__ A0, const unsigned short* __restrict__ BpkR,
    const float* __restrict__ sc, const float* __restrict__ sh,
    float* __restrict__ outf, int n){
  __shared__ unsigned short Ms[64*64];    // 8 KB mean-yl tile (bf16, perm2 positions)
  __shared__ unsigned short Bs[128*64];   // 16 KB BpkR
  __shared__ int scsr[AGGF_CAP];          // 8 KB staged csr window
  __shared__ int sw[2];
  int t = threadIdx.x;
  int n0 = blockIdx.x*64;
  if (t == 0){
    sw[0] = off[n0];
    int last = min(n0 + 63, n - 1);
    sw[1] = off[last] + deg[last];
  }
  {
    const uint4* s = (const uint4*)BpkR;
    uint4* d = (uint4*)Bs;
    #pragma unroll
    for (int i=0;i<4;i++) d[i*256 + t] = s[i*256 + t];
  }
  __syncthreads();
  int e0b = sw[0];
  int span = sw[1] - e0b;
  for (int i = t; i < span && i < AGGF_CAP; i += 256) scsr[i] = csr[e0b + i];
  __syncthreads();

  int lane = t & 63, w = t >> 6;
  int sl4 = lane & 3;

  // gather phase: 16 nodes/wave, 4 lanes x uint4 per node, one iteration
  {
    int rk = w*16 + (lane >> 2);
    int idx = n0 + rk;
    bool valid = idx < n;
    int s0 = valid ? off[idx] : 0;
    int s1 = valid ? (s0 + deg[idx]) : 0;
    f32x2 b0={0,0},b1={0,0},b2={0,0},b3={0,0},b4={0,0},b5={0,0},b6={0,0},b7={0,0};
    int e = s0;
    for (; e + 8 <= s1; e += 8){
      int le = e - e0b;
      int i0,i1,i2,i3,i4,i5,i6,i7;
      if (le + 8 <= AGGF_CAP){
        i0 = scsr[le];   i1 = scsr[le+1]; i2 = scsr[le+2]; i3 = scsr[le+3];
        i4 = scsr[le+4]; i5 = scsr[le+5]; i6 = scsr[le+6]; i7 = scsr[le+7];
      } else {
        i0 = csr[e];   i1 = csr[e+1]; i2 = csr[e+2]; i3 = csr[e+3];
        i4 = csr[e+4]; i5 = csr[e+5]; i6 = csr[e+6]; i7 = csr[e+7];
      }
      uint4 v0 = ylq4[(size_t)i0*4 + sl4];
      uint4 v1 = ylq4[(size_t)i1*4 + sl4];
      uint4 v2 = ylq4[(size_t)i2*4 + sl4];
      uint4 v3 = ylq4[(size_t)i3*4 + sl4];
      uint4 v4 = ylq4[(size_t)i4*4 + sl4];
      uint4 v5 = ylq4[(size_t)i5*4 + sl4];
      uint4 v6 = ylq4[(size_t)i6*4 + sl4];
      uint4 v7 = ylq4[(size_t)i7*4 + sl4];
      ACCP16(v0); ACCP16(v1); ACCP16(v2); ACCP16(v3);
      ACCP16(v4); ACCP16(v5); ACCP16(v6); ACCP16(v7);
    }
    for (; e + 4 <= s1; e += 4){
      int le = e - e0b;
      int i0,i1,i2,i3;
      if (le + 4 <= AGGF_CAP){
        i0 = scsr[le]; i1 = scsr[le+1]; i2 = scsr[le+2]; i3 = scsr[le+3];
      } else {
        i0 = csr[e]; i1 = csr[e+1]; i2 = csr[e+2]; i3 = csr[e+3];
      }
      uint4 v0 = ylq4[(size_t)i0*4 + sl4];
      uint4 v1 = ylq4[(size_t)i1*4 + sl4];
      uint4 v2 = ylq4[(size_t)i2*4 + sl4];
      uint4 v3 = ylq4[(size_t)i3*4 + sl4];
      ACCP16(v0); ACCP16(v1); ACCP16(v2); ACCP16(v3);
    }
    for (; e < s1; e++){
      int le = e - e0b;
      int ii = (le < AGGF_CAP) ? scsr[le] : csr[e];
      uint4 v = ylq4[(size_t)ii*4 + sl4];
      ACCP16(v);
    }
    int d = s1 - s0;
    float inv = 1.0f / (float)(d > 0 ? d : 1);
    uint4 o0, o1;
    o0.x = pack2(b0.x*inv, b0.y*inv);  o0.y = pack2(b1.x*inv, b1.y*inv);
    o0.z = pack2(b2.x*inv, b2.y*inv);  o0.w = pack2(b3.x*inv, b3.y*inv);
    o1.x = pack2(b4.x*inv, b4.y*inv);  o1.y = pack2(b5.x*inv, b5.y*inv);
    o1.z = pack2(b6.x*inv, b6.y*inv);  o1.w = pack2(b7.x*inv, b7.y*inv);
    ((uint4*)Ms)[rk*8 + sl4*2]     = o0;
    ((uint4*)Ms)[rk*8 + sl4*2 + 1] = o1;
  }
  __syncthreads();

  // GEMM phase: wave w owns rows [w*16, w*16+16); C = h_b @ Wr2^T (K=128), + mean-yl, BN, L2norm
  int quad = lane >> 4, c = lane & 15;
  int woff = w*16;
  int r0 = n0 + woff + c;
  f32x4 acc[4];
  #pragma unroll
  for (int nt=0;nt<4;nt++) acc[nt] = (f32x4){0.f,0.f,0.f,0.f};
  #pragma unroll
  for (int kk=0; kk<4; kk++){
    int ka = kk*32 + quad*8;
    short8 a0 = {0,0,0,0,0,0,0,0};
    if (r0 < n) a0 = *(const short8*)(A0 + (size_t)r0*128 + ka);
    #pragma unroll
    for (int nt=0; nt<4; nt++){
      short8 bb2 = *(const short8*)&Bs[(size_t)((kk*4 + nt)*64 + lane)*8];
      acc[nt] = __builtin_amdgcn_mfma_f32_16x16x32_bf16(a0, bb2, acc[nt], 0, 0, 0);
    }
  }

  float scv[4], shv[4];
  #pragma unroll
  for (int nt=0;nt<4;nt++){ scv[nt] = sc[nt*16 + c]; shv[nt] = sh[nt*16 + c]; }

  #pragma unroll
  for (int r=0;r<4;r++){
    int lr = woff + quad*4 + r;
    int row = n0 + lr;
    float v[4];
    float ss2 = 0.f;
    if (row < n){
      #pragma unroll
      for (int nt=0;nt<4;nt++){
        // Ms holds perm2 positions: channel nt*16+c lives at position c*4+nt
        float u = acc[nt][r] + bf2f(Ms[lr*64 + c*4 + nt]);
        u = u*scv[nt] + shv[nt];
        v[nt] = u;
        ss2 += u*u;
      }
    } else {
      #pragma unroll
      for (int nt=0;nt<4;nt++) v[nt] = 0.f;
    }
    ss2 += __shfl_xor(ss2, 1, 64);
    ss2 += __shfl_xor(ss2, 2, 64);
    ss2 += __shfl_xor(ss2, 4, 64);
    ss2 += __shfl_xor(ss2, 8, 64);
    float rn = 1.0f / fmaxf(sqrtf(ss2), 1e-12f);
    if (row < n){
      #pragma unroll
      for (int nt=0;nt<4;nt++) outf[(size_t)row*64 + nt*16 + c] = v[nt]*rn;
    }
  }
}

// ---------------- launcher ----------------

extern "C" void kernel_launch(void* const* d_in, const int* in_sizes, int n_in,
                              void* d_out, int out_size, void* d_ws, size_t ws_size,
                              hipStream_t stream){
  const float* x = (const float*)d_in[0];
  const int* ei  = (const int*)d_in[1];
  int N = in_sizes[0] / 128;
  int E = in_sizes[1] / 2;
  const int* esrc = ei;
  const int* edst = ei + E;
  int nbuck = CDIV(N, 128);
  int nb2 = 2*nbuck;

  const float *Wl[3], *bl[3], *Wr[3], *g[3], *bb[3], *rm[3], *rv[3];
  int dout[3];
  for (int i=0;i<3;i++){
    int base = 2 + 7*i;
    Wl[i]=(const float*)d_in[base];   bl[i]=(const float*)d_in[base+1];
    Wr[i]=(const float*)d_in[base+2]; g[i] =(const float*)d_in[base+3];
    bb[i]=(const float*)d_in[base+4]; rm[i]=(const float*)d_in[base+5];
    rv[i]=(const float*)d_in[base+6];
    dout[i] = in_sizes[base] / 128;
  }

  char* p = (char*)d_ws;
  size_t o = 0;
  auto alloc = [&](size_t bytes)->void*{ void* r = p + o; o += (bytes + 255) & ~(size_t)255; return r; };
  int* bz    = (int*)alloc((size_t)(nbuck + 1)*4);     // bcur | ovCnt (one memset)
  int* bcur  = bz;
  int* ovCnt = bz + nbuck;
  int* off   = (int*)alloc((size_t)N*4);
  int* deg   = (int*)alloc((size_t)N*4);
  int* csr   = (int*)alloc((size_t)nbuck*BUCK_CAP*4);
  unsigned* ebuf  = (unsigned*)alloc((size_t)nbuck*BUCK_CAP*4);
  unsigned* ovBuf = (unsigned*)alloc((size_t)E*4);
  unsigned* xb   = (unsigned*)alloc((size_t)N*64*4);   // bf16 x (natural)
  unsigned* xq   = (unsigned*)alloc((size_t)N*128);    // fp8 x (identity order)
  unsigned* h_a  = (unsigned*)alloc((size_t)N*64*4);   // bf16 h1 (natural)
  unsigned* haq  = (unsigned*)alloc((size_t)N*128);    // fp8 h1 (perm)
  unsigned* h_b  = (unsigned*)alloc((size_t)N*64*4);   // bf16 h2 (natural)
  unsigned* ylb  = (unsigned*)alloc((size_t)N*64);     // fp8 yl (perm2)
  unsigned short* Bpk01[2];
  float* sc[3]; float* sh[3];
  for (int i=0;i<2;i++) Bpk01[i] = (unsigned short*)alloc((size_t)256*dout[i]*2);
  unsigned short* BpkL = (unsigned short*)alloc((size_t)128*dout[2]*2);
  unsigned short* BpkR = (unsigned short*)alloc((size_t)128*dout[2]*2);
  for (int i=0;i<3;i++){
    sc[i] = (float*)alloc((size_t)dout[i]*4);
    sh[i] = (float*)alloc((size_t)dout[i]*4);
  }

  hipMemsetAsync(bz, 0, (size_t)(nbuck + 1)*4, stream);

  WtpArgs wa[4];
  wa[0] = { Wl[0], Wr[0], bl[0], g[0], bb[0], rm[0], rv[0], Bpk01[0], sc[0], sh[0], 8, dout[0], 1, CDIV(256*dout[0]+dout[0],256), 0 };
  wa[1] = { Wl[1], Wr[1], bl[1], g[1], bb[1], rm[1], rv[1], Bpk01[1], sc[1], sh[1], 8, dout[1], 1, CDIV(256*dout[1]+dout[1],256), 1 };
  wa[2] = { Wl[2], nullptr, nullptr, nullptr, nullptr, nullptr, nullptr, BpkL, nullptr, nullptr, 4, dout[2], 0, CDIV(128*dout[2],256), 0 };
  wa[3] = { Wr[2], nullptr, bl[2], g[2], bb[2], rm[2], rv[2], BpkR, sc[2], sh[2], 4, dout[2], 1, CDIV(128*dout[2]+dout[2],256), 0 };

  int castBlocks = CDIV(N*32, 256);
  int binBlocks  = CDIV(E, 256*16);
  int prepBlocks = castBlocks + binBlocks + wa[0].nblk + wa[1].nblk + wa[2].nblk + wa[3].nblk;
  k_prep<<<prepBlocks,256,0,stream>>>(x, N*32, xb, xq, esrc, edst, E, bcur, ovCnt, ebuf, ovBuf,
                                      nbuck, castBlocks, binBlocks,
                                      wa[0], wa[1], wa[2], wa[3]);

  // layer 0 (+ csr build): 64-node blocks; writes off/deg/csr for later layers
  k_bfuse<<<nb2,256,0,stream>>>(ebuf, bcur, ovCnt, ovBuf, N, off, deg, csr,
                                (const uint4*)xq, (const unsigned short*)xb,
                                Bpk01[0], sc[0], sh[0],
                                (unsigned short*)h_a, haq);
  // layer 1: fused gather(haq) + GEMM1 + yl mini-GEMM -> h_b + ylb
  k_fuse1<<<nb2,256,0,stream>>>((const uint4*)haq, off, deg, csr,
                                (const unsigned short*)h_a, Bpk01[1], sc[1], sh[1], BpkL,
                                (unsigned short*)h_b, ylb, N);
  // layer 2: fused mean-yl gather + final GEMM + BN + L2norm
  k_aggf<<<nb2,256,0,stream>>>((const uint4*)ylb, off, deg, csr,
                               (const unsigned short*)h_b, BpkR, sc[2], sh[2],
                               (float*)d_out, N);
}

// Round 9
// 208.123 us; speedup vs baseline: 3.1671x; 1.0414x over previous
//
#include <hip/hip_runtime.h>
#include <hip/hip_bf16.h>

#define CDIV(a,b) (((a)+(b)-1)/(b))
#define NBUCK_MAX 512   // 128-node ebuf buckets; supports N up to 65536 (ebuf packing needs N<=65536)
#define BUCK_CAP 3072   // fixed slots per 128-node bucket (mean 2046, +23 sigma; overflow list past that)
#define FUSE_CAP 1536   // staged csr entries per 64-node bfuse block (mean 1024)
#define CAPL     4096   // fuse1 csr window (fills the 16KB sBL4 region)
#define AGGF_CAP 2048   // aggf csr window

typedef __attribute__((ext_vector_type(8))) short short8;
typedef __attribute__((ext_vector_type(4))) float f32x4;
typedef __attribute__((ext_vector_type(2))) float f32x2;

static __device__ __forceinline__ unsigned short f2bf(float f){
  union { float f; unsigned u; } v; v.f = f;
  unsigned r = v.u + 0x7fffu + ((v.u >> 16) & 1u);   // RNE
  return (unsigned short)(r >> 16);
}
static __device__ __forceinline__ unsigned pack2(float lo, float hi){
  return (unsigned)f2bf(lo) | ((unsigned)f2bf(hi) << 16);
}
static __device__ __forceinline__ float bf2f(unsigned short s){
  union { unsigned u; float f; } v; v.u = ((unsigned)s) << 16; return v.f;
}
// pack 4 f32 -> 4 fp8 e4m3 bytes (byte0=a .. byte3=d)
static __device__ __forceinline__ unsigned pk_fp8x4(float a, float b, float c, float d){
  int v = __builtin_amdgcn_cvt_pk_fp8_f32(a, b, 0, false);
  v = __builtin_amdgcn_cvt_pk_fp8_f32(c, d, v, true);
  return (unsigned)v;
}

// accumulate 16 fp8 bytes (uint4) into f32x2 accumulators b0..b7 (v_pk_add_f32 path)
#define ACCP16(v) { b0 += __builtin_amdgcn_cvt_pk_f32_fp8((int)v.x, false); \
                    b1 += __builtin_amdgcn_cvt_pk_f32_fp8((int)v.x, true);  \
                    b2 += __builtin_amdgcn_cvt_pk_f32_fp8((int)v.y, false); \
                    b3 += __builtin_amdgcn_cvt_pk_f32_fp8((int)v.y, true);  \
                    b4 += __builtin_amdgcn_cvt_pk_f32_fp8((int)v.z, false); \
                    b5 += __builtin_amdgcn_cvt_pk_f32_fp8((int)v.z, true);  \
                    b6 += __builtin_amdgcn_cvt_pk_f32_fp8((int)v.w, false); \
                    b7 += __builtin_amdgcn_cvt_pk_f32_fp8((int)v.w, true); }

// ---------------- weight pack args ----------------
// perm: first-128 K positions hold channel pi(k) = (k&7)*16 + (k>>3) (matches gemm-epilogue fp8 row layout)

struct WtpArgs {
  const float *W0, *W1, *bl, *g, *b, *rm, *rv;
  unsigned short* Bpk; float *sc; float *sh;
  int kblk, dout, do_bn, nblk, perm;
};

static __device__ __forceinline__ void wtp_one(const WtpArgs& a, int idx){
  int NB16 = a.kblk*32*a.dout;
  if (idx < NB16){
    int j = idx & 7, lane = (idx >> 3) & 63, rest = idx >> 9;
    int NT = a.dout >> 4;
    int nt = rest % NT, kk = rest / NT;
    int nn = nt*16 + (lane & 15);
    int k  = kk*32 + ((lane >> 4) * 8) + j;
    float v;
    if (k < 128){
      int kc = a.perm ? (((k & 7) << 4) | (k >> 3)) : k;
      v = a.W0[nn*128 + kc];
    } else {
      v = a.W1[nn*128 + (k - 128)];
    }
    a.Bpk[idx] = f2bf(v);
  } else if (a.do_bn && idx < NB16 + a.dout){
    int jj = idx - NB16;
    float s = a.g[jj] * rsqrtf(a.rv[jj] + 1e-5f);
    a.sc[jj] = s;
    a.sh[jj] = (a.bl[jj] - a.rm[jj]) * s + a.b[jj];
  }
}

// ---------------- k_prep: cast x->bf16+fp8 (4 float4/thread) | edge binning into fixed-cap buckets | weight pack ----------------

__global__ __launch_bounds__(256) void k_prep(const float* __restrict__ x, int n4, unsigned* __restrict__ xb,
                                              unsigned* __restrict__ xq,
                                              const int* __restrict__ esrc, const int* __restrict__ edst,
                                              int E, int* __restrict__ bcur, int* __restrict__ ovCnt,
                                              unsigned* __restrict__ ebuf, unsigned* __restrict__ ovBuf,
                                              int nbuck, int castBlocks, int binBlocks,
                                              WtpArgs a0, WtpArgs a1, WtpArgs a2, WtpArgs a3){
  __shared__ int scnt[NBUCK_MAX];
  __shared__ int sbase[NBUCK_MAX];
  int b = blockIdx.x, t = threadIdx.x;
  if (b < castBlocks){
    int i0 = b*1024 + t;          // 4 float4-groups per thread, stride 256 (coalesced)
    #pragma unroll
    for (int j=0;j<4;j++){
      int i = i0 + j*256;
      if (i < n4){
        float4 v = ((const float4*)x)[i];
        uint2 o; o.x = pack2(v.x, v.y); o.y = pack2(v.z, v.w);
        ((uint2*)xb)[i] = o;
        xq[i] = pk_fp8x4(v.x, v.y, v.z, v.w);    // identity channel order
      }
    }
    return;
  }
  b -= castBlocks;
  if (b < binBlocks){
    for (int i=t;i<nbuck;i+=256) scnt[i] = 0;
    __syncthreads();
    constexpr int EPT = 16;
    int e0 = b*256*EPT;
    int bb[EPT]; unsigned pk[EPT];
    #pragma unroll
    for (int i=0;i<EPT;i++){
      int e = e0 + i*256 + t;
      if (e < E){
        int d = edst[e];
        bb[i] = d >> 7;
        pk[i] = ((unsigned)(d & 127) << 16) | (unsigned)esrc[e];
        atomicAdd(&scnt[bb[i]], 1);
      } else bb[i] = -1;
    }
    __syncthreads();
    for (int i=t;i<nbuck;i+=256){
      int c = scnt[i];
      sbase[i] = (c > 0) ? atomicAdd(&bcur[i], c) : 0;
      scnt[i] = 0;
    }
    __syncthreads();
    #pragma unroll
    for (int i=0;i<EPT;i++){
      if (bb[i] >= 0){
        int p = atomicAdd(&scnt[bb[i]], 1);
        int gpos = sbase[bb[i]] + p;
        if (gpos < BUCK_CAP) ebuf[(size_t)bb[i]*BUCK_CAP + gpos] = pk[i];
        else { int oi = atomicAdd(ovCnt, 1); ovBuf[oi] = ((unsigned)bb[i] << 23) | pk[i]; }
      }
    }
    return;
  }
  b -= binBlocks;
  if (b < a0.nblk){ wtp_one(a0, b*256 + t); return; }
  b -= a0.nblk;
  if (b < a1.nblk){ wtp_one(a1, b*256 + t); return; }
  b -= a1.nblk;
  if (b < a2.nblk){ wtp_one(a2, b*256 + t); return; }
  b -= a2.nblk;
  wtp_one(a3, b*256 + t);
}

// ---------------- k_bfuse: csr build + fused layer-0, 64-node blocks (two blocks share a 128-node bucket) ----------------
// Static bucket base b*BUCK_CAP: no global scan needed. Writes off[] (padded-absolute) + deg[].

__global__ __launch_bounds__(256, 4) void k_bfuse(
    const unsigned* __restrict__ ebuf, const int* __restrict__ bcur,
    const int* __restrict__ ovCnt, const unsigned* __restrict__ ovBuf, int N,
    int* __restrict__ off, int* __restrict__ deg, int* __restrict__ csr,
    const uint4* __restrict__ xq4, const unsigned short* __restrict__ Ag,
    const unsigned short* __restrict__ Bpk, const float* __restrict__ sc, const float* __restrict__ sh,
    unsigned short* __restrict__ outh, unsigned* __restrict__ outq){
  __shared__ uint4 Ms4[64*17];      // 17408 B mean tile (head reused as sdeg/sabs/cur during csr build)
  __shared__ int scsr[FUSE_CAP];    // 6144 B local csr (this block's 64-node half)
  unsigned short* Ms = (unsigned short*)Ms4;
  int* sdeg = (int*)Ms4;            // [128]
  int* sabs = sdeg + 128;           // [129] window-local offsets
  int* cur  = sabs + 129;           // [128]
  int wb = blockIdx.x;
  int b = wb >> 1, hi = wb & 1;
  int t = threadIdx.x;
  if (t < 128){ sdeg[t] = 0; cur[t] = 0; }
  __syncthreads();
  size_t bBase = (size_t)b*BUCK_CAP;
  int cntMain = min(bcur[b], BUCK_CAP);
  int ov = *ovCnt;
  for (int e = t; e < cntMain; e += 256)
    atomicAdd(&sdeg[ebuf[bBase + e] >> 16], 1);
  for (int i = t; i < ov; i += 256){
    unsigned v = ovBuf[i];
    if ((int)(v >> 23) == b) atomicAdd(&sdeg[(v >> 16) & 127u], 1);
  }
  __syncthreads();
  // scan 128 degrees -> window-local starts sabs[0..128]
  for (int d=1; d<128; d<<=1){
    int u = (t < 128 && t >= d) ? sdeg[t-d] : 0;
    __syncthreads();
    if (t < 128) sdeg[t] += u;
    __syncthreads();
  }
  if (t == 0) sabs[0] = 0;
  if (t < 128) sabs[t+1] = sdeg[t];
  __syncthreads();
  int base64 = sabs[hi*64];
  int myTot  = sabs[hi*64 + 64] - base64;
  int n0 = (b << 7) + hi*64;
  int cnt = (N > n0) ? min(64, N - n0) : 0;
  if (t < cnt){
    off[n0 + t] = (int)bBase + sabs[hi*64 + t];
    deg[n0 + t] = sabs[hi*64 + t + 1] - sabs[hi*64 + t];
  }
  // stash this thread's gather ranges before Ms region is reused
  int lane = t & 63, w = t >> 6, sl = lane & 7;
  int gs0[2], gs1[2];
  #pragma unroll
  for (int it=0; it<2; it++){
    int rk = w*16 + it*8 + (lane >> 3);          // local row 0..63
    gs0[it] = sabs[hi*64 + rk] - base64;
    gs1[it] = sabs[hi*64 + rk + 1] - base64;
  }
  bool fits = myTot <= FUSE_CAP;
  // scatter own-half edges into local csr (LDS if fits, else global)
  for (int e = t; e < cntMain; e += 256){
    unsigned pr = ebuf[bBase + e];
    int ln = (int)(pr >> 16);
    if ((ln >> 6) == hi){
      int p = atomicAdd(&cur[ln], 1);
      int gpos = sabs[ln] + p;                    // position within full window
      int sv = (int)(pr & 0xffffu);
      if (fits) scsr[gpos - base64] = sv;
      else      csr[bBase + gpos] = sv;
    }
  }
  for (int i = t; i < ov; i += 256){
    unsigned v = ovBuf[i];
    if ((int)(v >> 23) == b){
      int ln = (int)((v >> 16) & 127u);
      if ((ln >> 6) == hi){
        int p = atomicAdd(&cur[ln], 1);
        int gpos = sabs[ln] + p;
        int sv = (int)(v & 0xffffu);
        if (fits) scsr[gpos - base64] = sv;
        else      csr[bBase + gpos] = sv;
      }
    }
  }
  __syncthreads();
  const int* gcsr = csr + bBase + base64;
  if (fits){
    for (int i = t; i < myTot; i += 256) csr[bBase + base64 + i] = scsr[i];
  } else {
    for (int i = t; i < FUSE_CAP; i += 256) scsr[i] = gcsr[i];
    __syncthreads();
  }

  // ---- gather phase: 8 lanes x uint4 per node, 16 nodes/wave ----
  #pragma unroll
  for (int it=0; it<2; it++){
    int rk = w*16 + it*8 + (lane >> 3);
    int s0 = gs0[it], s1 = gs1[it];
    f32x2 b0={0,0},b1={0,0},b2={0,0},b3={0,0},b4={0,0},b5={0,0},b6={0,0},b7={0,0};
    int e = s0;
    for (; e + 8 <= s1; e += 8){
      int i0,i1,i2,i3,i4,i5,i6,i7;
      if (e + 8 <= FUSE_CAP){
        i0 = scsr[e];   i1 = scsr[e+1]; i2 = scsr[e+2]; i3 = scsr[e+3];
        i4 = scsr[e+4]; i5 = scsr[e+5]; i6 = scsr[e+6]; i7 = scsr[e+7];
      } else {
        i0 = gcsr[e];   i1 = gcsr[e+1]; i2 = gcsr[e+2]; i3 = gcsr[e+3];
        i4 = gcsr[e+4]; i5 = gcsr[e+5]; i6 = gcsr[e+6]; i7 = gcsr[e+7];
      }
      uint4 v0 = xq4[(size_t)i0*8 + sl];
      uint4 v1 = xq4[(size_t)i1*8 + sl];
      uint4 v2 = xq4[(size_t)i2*8 + sl];
      uint4 v3 = xq4[(size_t)i3*8 + sl];
      uint4 v4 = xq4[(size_t)i4*8 + sl];
      uint4 v5 = xq4[(size_t)i5*8 + sl];
      uint4 v6 = xq4[(size_t)i6*8 + sl];
      uint4 v7 = xq4[(size_t)i7*8 + sl];
      ACCP16(v0); ACCP16(v1); ACCP16(v2); ACCP16(v3);
      ACCP16(v4); ACCP16(v5); ACCP16(v6); ACCP16(v7);
    }
    for (; e + 4 <= s1; e += 4){
      int i0,i1,i2,i3;
      if (e + 4 <= FUSE_CAP){
        i0 = scsr[e]; i1 = scsr[e+1]; i2 = scsr[e+2]; i3 = scsr[e+3];
      } else {
        i0 = gcsr[e]; i1 = gcsr[e+1]; i2 = gcsr[e+2]; i3 = gcsr[e+3];
      }
      uint4 v0 = xq4[(size_t)i0*8 + sl];
      uint4 v1 = xq4[(size_t)i1*8 + sl];
      uint4 v2 = xq4[(size_t)i2*8 + sl];
      uint4 v3 = xq4[(size_t)i3*8 + sl];
      ACCP16(v0); ACCP16(v1); ACCP16(v2); ACCP16(v3);
    }
    for (; e < s1; e++){
      int ii = (e < FUSE_CAP) ? scsr[e] : gcsr[e];
      uint4 v = xq4[(size_t)ii*8 + sl];
      ACCP16(v);
    }
    int d = s1 - s0;
    float inv = 1.0f / (float)(d > 0 ? d : 1);
    uint4 o0, o1;
    o0.x = pack2(b0.x*inv, b0.y*inv);  o0.y = pack2(b1.x*inv, b1.y*inv);
    o0.z = pack2(b2.x*inv, b2.y*inv);  o0.w = pack2(b3.x*inv, b3.y*inv);
    o1.x = pack2(b4.x*inv, b4.y*inv);  o1.y = pack2(b5.x*inv, b5.y*inv);
    o1.z = pack2(b6.x*inv, b6.y*inv);  o1.w = pack2(b7.x*inv, b7.y*inv);
    Ms4[rk*17 + sl*2]     = o0;
    Ms4[rk*17 + sl*2 + 1] = o1;
  }
  __syncthreads();

  // ---- GEMM phase: C = [mean | Ag] @ B (K=256), BN + ReLU; wave w owns rows [w*16, w*16+16) ----
  int quad = lane >> 4, c = lane & 15;
  int woff = w*16;
  int r0 = n0 + woff + c;

  f32x4 acc[8];
  #pragma unroll
  for (int nt=0;nt<8;nt++) acc[nt] = (f32x4){0.f,0.f,0.f,0.f};

  #pragma unroll
  for (int kk=0; kk<8; kk++){
    int ka = (kk & 3)*32 + quad*8;
    short8 a0;
    if (kk < 4){
      a0 = *(const short8*)&Ms[(woff + c)*136 + ka];
    } else {
      a0 = (short8){0,0,0,0,0,0,0,0};
      if (r0 < N) a0 = *(const short8*)(Ag + (size_t)r0*128 + ka);
    }
    #pragma unroll
    for (int nt=0; nt<8; nt++){
      short8 bb2 = *(const short8*)(Bpk + (size_t)((kk*8 + nt)*64 + lane)*8);
      acc[nt] = __builtin_amdgcn_mfma_f32_16x16x32_bf16(a0, bb2, acc[nt], 0, 0, 0);
    }
  }

  float scv[8], shv[8];
  #pragma unroll
  for (int nt=0;nt<8;nt++){ scv[nt] = sc[nt*16 + c]; shv[nt] = sh[nt*16 + c]; }

  #pragma unroll
  for (int r=0;r<4;r++){
    int row = n0 + woff + quad*4 + r;
    if (row < N){
      float u[8];
      #pragma unroll
      for (int nt=0;nt<8;nt++){
        float uu = acc[nt][r]*scv[nt] + shv[nt];
        u[nt] = fmaxf(uu, 0.f);
        outh[(size_t)row*128 + nt*16 + c] = f2bf(u[nt]);
      }
      // fp8(perm) copy: bytes row*128 + c*8 + j hold channel j*16+c
      uint2 q;
      q.x = pk_fp8x4(u[0], u[1], u[2], u[3]);
      q.y = pk_fp8x4(u[4], u[5], u[6], u[7]);
      ((uint2*)outq)[(size_t)row*16 + c] = q;
    }
  }
}

// ---------------- k_fuse1: fused layer-1 (gather haq + GEMM1 + yl mini-GEMM), 64-node blocks ----------------

__global__ __launch_bounds__(256, 4) void k_fuse1(
    const uint4* __restrict__ hq4, const int* __restrict__ off, const int* __restrict__ deg,
    const int* __restrict__ csr,
    const unsigned short* __restrict__ Ag, const unsigned short* __restrict__ Bpk,
    const float* __restrict__ sc, const float* __restrict__ sh,
    const unsigned short* __restrict__ BpkL,
    unsigned short* __restrict__ outh, unsigned* __restrict__ outyl, int n){
  __shared__ uint4 Ms4[64*17];      // 17408 B
  __shared__ uint4 sBL4[1024];      // 16384 B: csr window (gather) -> BpkL stage (yl phase)
  __shared__ int sw[2];
  unsigned short* Ms = (unsigned short*)Ms4;
  int* scsr = (int*)sBL4;
  int t = threadIdx.x;
  int n0 = blockIdx.x*64;
  if (t == 0){
    sw[0] = off[n0];
    int last = min(n0 + 63, n - 1);
    sw[1] = off[last] + deg[last];
  }
  __syncthreads();
  int e0b = sw[0];
  int span = sw[1] - e0b;
  for (int i = t; i < span && i < CAPL; i += 256) scsr[i] = csr[e0b + i];
  __syncthreads();

  int lane = t & 63, w = t >> 6;
  int sl = lane & 7;

  // ---- gather phase: 16 nodes/wave ----
  #pragma unroll
  for (int it=0; it<2; it++){
    int rk = w*16 + it*8 + (lane >> 3);
    int idx = n0 + rk;
    bool valid = idx < n;
    int s0 = valid ? off[idx] : 0;
    int s1 = valid ? (s0 + deg[idx]) : 0;
    f32x2 b0={0,0},b1={0,0},b2={0,0},b3={0,0},b4={0,0},b5={0,0},b6={0,0},b7={0,0};
    int e = s0;
    for (; e + 8 <= s1; e += 8){
      int le = e - e0b;
      int i0,i1,i2,i3,i4,i5,i6,i7;
      if (le + 8 <= CAPL){
        i0 = scsr[le];   i1 = scsr[le+1]; i2 = scsr[le+2]; i3 = scsr[le+3];
        i4 = scsr[le+4]; i5 = scsr[le+5]; i6 = scsr[le+6]; i7 = scsr[le+7];
      } else {
        i0 = csr[e];   i1 = csr[e+1]; i2 = csr[e+2]; i3 = csr[e+3];
        i4 = csr[e+4]; i5 = csr[e+5]; i6 = csr[e+6]; i7 = csr[e+7];
      }
      uint4 v0 = hq4[(size_t)i0*8 + sl];
      uint4 v1 = hq4[(size_t)i1*8 + sl];
      uint4 v2 = hq4[(size_t)i2*8 + sl];
      uint4 v3 = hq4[(size_t)i3*8 + sl];
      uint4 v4 = hq4[(size_t)i4*8 + sl];
      uint4 v5 = hq4[(size_t)i5*8 + sl];
      uint4 v6 = hq4[(size_t)i6*8 + sl];
      uint4 v7 = hq4[(size_t)i7*8 + sl];
      ACCP16(v0); ACCP16(v1); ACCP16(v2); ACCP16(v3);
      ACCP16(v4); ACCP16(v5); ACCP16(v6); ACCP16(v7);
    }
    for (; e + 4 <= s1; e += 4){
      int le = e - e0b;
      int i0,i1,i2,i3;
      if (le + 4 <= CAPL){
        i0 = scsr[le]; i1 = scsr[le+1]; i2 = scsr[le+2]; i3 = scsr[le+3];
      } else {
        i0 = csr[e]; i1 = csr[e+1]; i2 = csr[e+2]; i3 = csr[e+3];
      }
      uint4 v0 = hq4[(size_t)i0*8 + sl];
      uint4 v1 = hq4[(size_t)i1*8 + sl];
      uint4 v2 = hq4[(size_t)i2*8 + sl];
      uint4 v3 = hq4[(size_t)i3*8 + sl];
      ACCP16(v0); ACCP16(v1); ACCP16(v2); ACCP16(v3);
    }
    for (; e < s1; e++){
      int le = e - e0b;
      int ii = (le < CAPL) ? scsr[le] : csr[e];
      uint4 v = hq4[(size_t)ii*8 + sl];
      ACCP16(v);
    }
    int d = s1 - s0;
    float inv = 1.0f / (float)(d > 0 ? d : 1);
    uint4 o0, o1;
    o0.x = pack2(b0.x*inv, b0.y*inv);  o0.y = pack2(b1.x*inv, b1.y*inv);
    o0.z = pack2(b2.x*inv, b2.y*inv);  o0.w = pack2(b3.x*inv, b3.y*inv);
    o1.x = pack2(b4.x*inv, b4.y*inv);  o1.y = pack2(b5.x*inv, b5.y*inv);
    o1.z = pack2(b6.x*inv, b6.y*inv);  o1.w = pack2(b7.x*inv, b7.y*inv);
    Ms4[rk*17 + sl*2]     = o0;
    Ms4[rk*17 + sl*2 + 1] = o1;
  }
  __syncthreads();

  // ---- GEMM phase: wave w owns rows [w*16, w*16+16) ----
  int quad = lane >> 4, c = lane & 15;
  int woff = w*16;
  int r0 = n0 + woff + c;

  f32x4 acc[8];
  #pragma unroll
  for (int nt=0;nt<8;nt++) acc[nt] = (f32x4){0.f,0.f,0.f,0.f};

  #pragma unroll
  for (int kk=0; kk<8; kk++){
    int ka = (kk & 3)*32 + quad*8;
    short8 a0;
    if (kk < 4){
      a0 = *(const short8*)&Ms[(woff + c)*136 + ka];
    } else {
      a0 = (short8){0,0,0,0,0,0,0,0};
      if (r0 < n) a0 = *(const short8*)(Ag + (size_t)r0*128 + ka);
    }
    #pragma unroll
    for (int nt=0; nt<8; nt++){
      short8 bb2 = *(const short8*)(Bpk + (size_t)((kk*8 + nt)*64 + lane)*8);
      acc[nt] = __builtin_amdgcn_mfma_f32_16x16x32_bf16(a0, bb2, acc[nt], 0, 0, 0);
    }
  }

  float scv[8], shv[8];
  #pragma unroll
  for (int nt=0;nt<8;nt++){ scv[nt] = sc[nt*16 + c]; shv[nt] = sh[nt*16 + c]; }

  __syncthreads();   // all A-reads of Ms done before epilogue overwrites it

  #pragma unroll
  for (int r=0;r<4;r++){
    int lrow = woff + quad*4 + r;
    int row = n0 + lrow;
    if (row < n){
      float u[8];
      #pragma unroll
      for (int nt=0;nt<8;nt++){
        float uu = acc[nt][r]*scv[nt] + shv[nt];
        u[nt] = fmaxf(uu, 0.f);
        outh[(size_t)row*128 + nt*16 + c] = f2bf(u[nt]);
      }
      #pragma unroll
      for (int nt=0;nt<8;nt++) Ms[lrow*136 + nt*16 + c] = f2bf(u[nt]);
    } else {
      #pragma unroll
      for (int nt=0;nt<8;nt++) Ms[lrow*136 + nt*16 + c] = 0;
    }
  }

  // stage BpkL (128x64 bf16 = 1024 uint4) into the csr-window region
  {
    const uint4* sL = (const uint4*)BpkL;
    #pragma unroll
    for (int i=0;i<4;i++) sBL4[i*256 + t] = sL[i*256 + t];
  }
  __syncthreads();
  unsigned short* BsL = (unsigned short*)sBL4;
  f32x4 acc2[4];
  #pragma unroll
  for (int nt=0;nt<4;nt++) acc2[nt] = (f32x4){0.f,0.f,0.f,0.f};
  int r0l = woff + c;
  #pragma unroll
  for (int kk=0; kk<4; kk++){
    int ka = kk*32 + quad*8;
    short8 a0 = *(const short8*)&Ms[r0l*136 + ka];
    #pragma unroll
    for (int nt=0; nt<4; nt++){
      short8 bb2 = *(const short8*)&BsL[(size_t)((kk*4 + nt)*64 + lane)*8];
      acc2[nt] = __builtin_amdgcn_mfma_f32_16x16x32_bf16(a0, bb2, acc2[nt], 0, 0, 0);
    }
  }
  #pragma unroll
  for (int r=0;r<4;r++){
    int row = n0 + woff + quad*4 + r;
    if (row < n){
      // fp8(perm2): byte row*64 + c*4 + nt holds channel nt*16+c
      unsigned q = pk_fp8x4(acc2[0][r], acc2[1][r], acc2[2][r], acc2[3][r]);
      outyl[(size_t)row*16 + c] = q;
    }
  }
}

// ---------------- fused layer-3: mean-yl gather (64-dim fp8) + GEMM (h_b@Wr2^T) + BN + L2norm, 64-node blocks ----------------

__global__ __launch_bounds__(256, 4) void k_aggf(
    const uint4* __restrict__ ylq4, const int* __restrict__ off, const int* __restrict__ deg,
    const int* __restrict__ csr,
    const unsigned short* __restrict__ A0, const unsigned short* __restrict__ BpkR,
    const float* __restrict__ sc, const float* __restrict__ sh,
    float* __restrict__ outf, int n){
  __shared__ unsigned short Ms[64*64];    // 8 KB mean-yl tile (bf16, perm2 positions)
  __shared__ unsigned short Bs[128*64];   // 16 KB BpkR
  __shared__ int scsr[AGGF_CAP];          // 8 KB staged csr window
  __shared__ int sw[2];
  int t = threadIdx.x;
  int n0 = blockIdx.x*64;
  if (t == 0){
    sw[0] = off[n0];
    int last = min(n0 + 63, n - 1);
    sw[1] = off[last] + deg[last];
  }
  {
    const uint4* s = (const uint4*)BpkR;
    uint4* d = (uint4*)Bs;
    #pragma unroll
    for (int i=0;i<4;i++) d[i*256 + t] = s[i*256 + t];
  }
  __syncthreads();
  int e0b = sw[0];
  int span = sw[1] - e0b;
  for (int i = t; i < span && i < AGGF_CAP; i += 256) scsr[i] = csr[e0b + i];
  __syncthreads();

  int lane = t & 63, w = t >> 6;
  int sl4 = lane & 3;

  // gather phase: 16 nodes/wave, 4 lanes x uint4 per node, one iteration
  {
    int rk = w*16 + (lane >> 2);
    int idx = n0 + rk;
    bool valid = idx < n;
    int s0 = valid ? off[idx] : 0;
    int s1 = valid ? (s0 + deg[idx]) : 0;
    f32x2 b0={0,0},b1={0,0},b2={0,0},b3={0,0},b4={0,0},b5={0,0},b6={0,0},b7={0,0};
    int e = s0;
    for (; e + 8 <= s1; e += 8){
      int le = e - e0b;
      int i0,i1,i2,i3,i4,i5,i6,i7;
      if (le + 8 <= AGGF_CAP){
        i0 = scsr[le];   i1 = scsr[le+1]; i2 = scsr[le+2]; i3 = scsr[le+3];
        i4 = scsr[le+4]; i5 = scsr[le+5]; i6 = scsr[le+6]; i7 = scsr[le+7];
      } else {
        i0 = csr[e];   i1 = csr[e+1]; i2 = csr[e+2]; i3 = csr[e+3];
        i4 = csr[e+4]; i5 = csr[e+5]; i6 = csr[e+6]; i7 = csr[e+7];
      }
      uint4 v0 = ylq4[(size_t)i0*4 + sl4];
      uint4 v1 = ylq4[(size_t)i1*4 + sl4];
      uint4 v2 = ylq4[(size_t)i2*4 + sl4];
      uint4 v3 = ylq4[(size_t)i3*4 + sl4];
      uint4 v4 = ylq4[(size_t)i4*4 + sl4];
      uint4 v5 = ylq4[(size_t)i5*4 + sl4];
      uint4 v6 = ylq4[(size_t)i6*4 + sl4];
      uint4 v7 = ylq4[(size_t)i7*4 + sl4];
      ACCP16(v0); ACCP16(v1); ACCP16(v2); ACCP16(v3);
      ACCP16(v4); ACCP16(v5); ACCP16(v6); ACCP16(v7);
    }
    for (; e + 4 <= s1; e += 4){
      int le = e - e0b;
      int i0,i1,i2,i3;
      if (le + 4 <= AGGF_CAP){
        i0 = scsr[le]; i1 = scsr[le+1]; i2 = scsr[le+2]; i3 = scsr[le+3];
      } else {
        i0 = csr[e]; i1 = csr[e+1]; i2 = csr[e+2]; i3 = csr[e+3];
      }
      uint4 v0 = ylq4[(size_t)i0*4 + sl4];
      uint4 v1 = ylq4[(size_t)i1*4 + sl4];
      uint4 v2 = ylq4[(size_t)i2*4 + sl4];
      uint4 v3 = ylq4[(size_t)i3*4 + sl4];
      ACCP16(v0); ACCP16(v1); ACCP16(v2); ACCP16(v3);
    }
    for (; e < s1; e++){
      int le = e - e0b;
      int ii = (le < AGGF_CAP) ? scsr[le] : csr[e];
      uint4 v = ylq4[(size_t)ii*4 + sl4];
      ACCP16(v);
    }
    int d = s1 - s0;
    float inv = 1.0f / (float)(d > 0 ? d : 1);
    uint4 o0, o1;
    o0.x = pack2(b0.x*inv, b0.y*inv);  o0.y = pack2(b1.x*inv, b1.y*inv);
    o0.z = pack2(b2.x*inv, b2.y*inv);  o0.w = pack2(b3.x*inv, b3.y*inv);
    o1.x = pack2(b4.x*inv, b4.y*inv);  o1.y = pack2(b5.x*inv, b5.y*inv);
    o1.z = pack2(b6.x*inv, b6.y*inv);  o1.w = pack2(b7.x*inv, b7.y*inv);
    ((uint4*)Ms)[rk*8 + sl4*2]     = o0;
    ((uint4*)Ms)[rk*8 + sl4*2 + 1] = o1;
  }
  __syncthreads();

  // GEMM phase: wave w owns rows [w*16, w*16+16); C = h_b @ Wr2^T (K=128), + mean-yl, BN, L2norm
  int quad = lane >> 4, c = lane & 15;
  int woff = w*16;
  int r0 = n0 + woff + c;
  f32x4 acc[4];
  #pragma unroll
  for (int nt=0;nt<4;nt++) acc[nt] = (f32x4){0.f,0.f,0.f,0.f};
  #pragma unroll
  for (int kk=0; kk<4; kk++){
    int ka = kk*32 + quad*8;
    short8 a0 = {0,0,0,0,0,0,0,0};
    if (r0 < n) a0 = *(const short8*)(A0 + (size_t)r0*128 + ka);
    #pragma unroll
    for (int nt=0; nt<4; nt++){
      short8 bb2 = *(const short8*)&Bs[(size_t)((kk*4 + nt)*64 + lane)*8];
      acc[nt] = __builtin_amdgcn_mfma_f32_16x16x32_bf16(a0, bb2, acc[nt], 0, 0, 0);
    }
  }

  float scv[4], shv[4];
  #pragma unroll
  for (int nt=0;nt<4;nt++){ scv[nt] = sc[nt*16 + c]; shv[nt] = sh[nt*16 + c]; }

  #pragma unroll
  for (int r=0;r<4;r++){
    int lr = woff + quad*4 + r;
    int row = n0 + lr;
    float v[4];
    float ss2 = 0.f;
    if (row < n){
      #pragma unroll
      for (int nt=0;nt<4;nt++){
        // Ms holds perm2 positions: channel nt*16+c lives at position c*4+nt
        float u = acc[nt][r] + bf2f(Ms[lr*64 + c*4 + nt]);
        u = u*scv[nt] + shv[nt];
        v[nt] = u;
        ss2 += u*u;
      }
    } else {
      #pragma unroll
      for (int nt=0;nt<4;nt++) v[nt] = 0.f;
    }
    ss2 += __shfl_xor(ss2, 1, 64);
    ss2 += __shfl_xor(ss2, 2, 64);
    ss2 += __shfl_xor(ss2, 4, 64);
    ss2 += __shfl_xor(ss2, 8, 64);
    float rn = 1.0f / fmaxf(sqrtf(ss2), 1e-12f);
    if (row < n){
      #pragma unroll
      for (int nt=0;nt<4;nt++) outf[(size_t)row*64 + nt*16 + c] = v[nt]*rn;
    }
  }
}

// ---------------- launcher ----------------

extern "C" void kernel_launch(void* const* d_in, const int* in_sizes, int n_in,
                              void* d_out, int out_size, void* d_ws, size_t ws_size,
                              hipStream_t stream){
  const float* x = (const float*)d_in[0];
  const int* ei  = (const int*)d_in[1];
  int N = in_sizes[0] / 128;
  int E = in_sizes[1] / 2;
  const int* esrc = ei;
  const int* edst = ei + E;
  int nbuck = CDIV(N, 128);
  int nb2 = 2*nbuck;

  const float *Wl[3], *bl[3], *Wr[3], *g[3], *bb[3], *rm[3], *rv[3];
  int dout[3];
  for (int i=0;i<3;i++){
    int base = 2 + 7*i;
    Wl[i]=(const float*)d_in[base];   bl[i]=(const float*)d_in[base+1];
    Wr[i]=(const float*)d_in[base+2]; g[i] =(const float*)d_in[base+3];
    bb[i]=(const float*)d_in[base+4]; rm[i]=(const float*)d_in[base+5];
    rv[i]=(const float*)d_in[base+6];
    dout[i] = in_sizes[base] / 128;
  }

  char* p = (char*)d_ws;
  size_t o = 0;
  auto alloc = [&](size_t bytes)->void*{ void* r = p + o; o += (bytes + 255) & ~(size_t)255; return r; };
  int* bz    = (int*)alloc((size_t)(nbuck + 1)*4);     // bcur | ovCnt (one memset)
  int* bcur  = bz;
  int* ovCnt = bz + nbuck;
  int* off   = (int*)alloc((size_t)N*4);
  int* deg   = (int*)alloc((size_t)N*4);
  int* csr   = (int*)alloc((size_t)nbuck*BUCK_CAP*4);
  unsigned* ebuf  = (unsigned*)alloc((size_t)nbuck*BUCK_CAP*4);
  unsigned* ovBuf = (unsigned*)alloc((size_t)E*4);
  unsigned* xb   = (unsigned*)alloc((size_t)N*64*4);   // bf16 x (natural)
  unsigned* xq   = (unsigned*)alloc((size_t)N*128);    // fp8 x (identity order)
  unsigned* h_a  = (unsigned*)alloc((size_t)N*64*4);   // bf16 h1 (natural)
  unsigned* haq  = (unsigned*)alloc((size_t)N*128);    // fp8 h1 (perm)
  unsigned* h_b  = (unsigned*)alloc((size_t)N*64*4);   // bf16 h2 (natural)
  unsigned* ylb  = (unsigned*)alloc((size_t)N*64);     // fp8 yl (perm2)
  unsigned short* Bpk01[2];
  float* sc[3]; float* sh[3];
  for (int i=0;i<2;i++) Bpk01[i] = (unsigned short*)alloc((size_t)256*dout[i]*2);
  unsigned short* BpkL = (unsigned short*)alloc((size_t)128*dout[2]*2);
  unsigned short* BpkR = (unsigned short*)alloc((size_t)128*dout[2]*2);
  for (int i=0;i<3;i++){
    sc[i] = (float*)alloc((size_t)dout[i]*4);
    sh[i] = (float*)alloc((size_t)dout[i]*4);
  }

  hipMemsetAsync(bz, 0, (size_t)(nbuck + 1)*4, stream);

  WtpArgs wa[4];
  wa[0] = { Wl[0], Wr[0], bl[0], g[0], bb[0], rm[0], rv[0], Bpk01[0], sc[0], sh[0], 8, dout[0], 1, CDIV(256*dout[0]+dout[0],256), 0 };
  wa[1] = { Wl[1], Wr[1], bl[1], g[1], bb[1], rm[1], rv[1], Bpk01[1], sc[1], sh[1], 8, dout[1], 1, CDIV(256*dout[1]+dout[1],256), 1 };
  wa[2] = { Wl[2], nullptr, nullptr, nullptr, nullptr, nullptr, nullptr, BpkL, nullptr, nullptr, 4, dout[2], 0, CDIV(128*dout[2],256), 0 };
  wa[3] = { Wr[2], nullptr, bl[2], g[2], bb[2], rm[2], rv[2], BpkR, sc[2], sh[2], 4, dout[2], 1, CDIV(128*dout[2]+dout[2],256), 0 };

  int castBlocks = CDIV(N*32, 256*4);
  int binBlocks  = CDIV(E, 256*16);
  int prepBlocks = castBlocks + binBlocks + wa[0].nblk + wa[1].nblk + wa[2].nblk + wa[3].nblk;
  k_prep<<<prepBlocks,256,0,stream>>>(x, N*32, xb, xq, esrc, edst, E, bcur, ovCnt, ebuf, ovBuf,
                                      nbuck, castBlocks, binBlocks,
                                      wa[0], wa[1], wa[2], wa[3]);

  // layer 0 (+ csr build): 64-node blocks; writes off/deg/csr for later layers
  k_bfuse<<<nb2,256,0,stream>>>(ebuf, bcur, ovCnt, ovBuf, N, off, deg, csr,
                                (const uint4*)xq, (const unsigned short*)xb,
                                Bpk01[0], sc[0], sh[0],
                                (unsigned short*)h_a, haq);
  // layer 1: fused gather(haq) + GEMM1 + yl mini-GEMM -> h_b + ylb
  k_fuse1<<<nb2,256,0,stream>>>((const uint4*)haq, off, deg, csr,
                                (const unsigned short*)h_a, Bpk01[1], sc[1], sh[1], BpkL,
                                (unsigned short*)h_b, ylb, N);
  // layer 2: fused mean-yl gather + final GEMM + BN + L2norm
  k_aggf<<<nb2,256,0,stream>>>((const uint4*)ylb, off, deg, csr,
                               (const unsigned short*)h_b, BpkR, sc[2], sh[2],
                               (float*)d_out, N);
}